// Round 6
// baseline (182.871 us; speedup 1.0000x reference)
//
#include <hip/hip_runtime.h>
#include <hip/hip_bf16.h>
#include <math.h>

#define Bsz 4
#define Slen 2048
#define Hdim 576
#define NH 9
#define NKV 3
#define HD 64
#define MAXPOS 8192

typedef __bf16 bf16_t;
typedef __bf16 bf16x8 __attribute__((ext_vector_type(8)));
typedef float f32x4 __attribute__((ext_vector_type(4)));
typedef float f32x16 __attribute__((ext_vector_type(16)));
typedef unsigned int u32;
typedef unsigned int u32x4 __attribute__((ext_vector_type(4)));

static __device__ __forceinline__ bf16x8 load_cvt8(const float* __restrict__ src){
  float4 f0 = *reinterpret_cast<const float4*>(src);
  float4 f1 = *reinterpret_cast<const float4*>(src + 4);
  bf16x8 v;
  v[0]=(bf16_t)f0.x; v[1]=(bf16_t)f0.y; v[2]=(bf16_t)f0.z; v[3]=(bf16_t)f0.w;
  v[4]=(bf16_t)f1.x; v[5]=(bf16_t)f1.y; v[6]=(bf16_t)f1.z; v[7]=(bf16_t)f1.w;
  return v;
}

// async global->LDS, 16B per lane
static __device__ __forceinline__ void gload16(const bf16_t* g, bf16_t* l){
  __builtin_amdgcn_global_load_lds((const __attribute__((address_space(1))) void*)g,
                                   (__attribute__((address_space(3))) void*)l, 16, 0, 0);
}

// ---------------- RoPE tables (positions 0..Slen-1 used) ----------------
__global__ void rope_table_kernel(float* __restrict__ cost, float* __restrict__ sint){
  int i = blockIdx.x * blockDim.x + threadIdx.x;
  if (i >= Slen * 32) return;
  int j = i & 31;
  int p = i >> 5;
  double invf = pow(100000.0, -(double)j / 32.0);
  double ang = (double)p * invf;
  cost[i] = (float)cos(ang);
  sint[i] = (float)sin(ang);
}

// ---------------- QKV projection GEMM (M=8192, K=576, N=960) ----------------
__launch_bounds__(256)
__global__ void qkv_gemm_kernel(const float* __restrict__ X,
                                const float* __restrict__ Wq,
                                const float* __restrict__ Wk,
                                const float* __restrict__ Wv,
                                bf16_t* __restrict__ qbuf,
                                bf16_t* __restrict__ kbuf,
                                bf16_t* __restrict__ vtbuf)
{
  __shared__ bf16_t Ald[128 * 72];
  __shared__ bf16_t Bld[64 * 72];
  const int t = threadIdx.x;
  const int l = t & 63;
  const int wid = t >> 6;
  const int wm = wid >> 1, wn = wid & 1;
  const int lane16 = l & 15, grp = l >> 4;
  const int m0 = blockIdx.x * 128;
  const int nt = blockIdx.y;

  const float* Wsrc;
  int nrow0;
  if (nt < 9)      { Wsrc = Wq; nrow0 = nt * 64; }
  else if (nt < 12){ Wsrc = Wk; nrow0 = (nt - 9) * 64; }
  else             { Wsrc = Wv; nrow0 = (nt - 12) * 64; }

  const f32x4 fzero = {0.f, 0.f, 0.f, 0.f};
  f32x4 acc[4][2];
  #pragma unroll
  for (int mi = 0; mi < 4; ++mi)
    #pragma unroll
    for (int ni = 0; ni < 2; ++ni)
      acc[mi][ni] = fzero;

  const int rA = t >> 1, kA = (t & 1) * 32;
  const int rB = t >> 2, kB = (t & 3) * 16;

  for (int kt = 0; kt < 9; ++kt){
    {
      const float* asrc = X + (size_t)(m0 + rA) * Hdim + kt * 64 + kA;
      bf16_t* adst = Ald + rA * 72 + kA;
      #pragma unroll
      for (int u = 0; u < 4; ++u)
        *reinterpret_cast<bf16x8*>(adst + u * 8) = load_cvt8(asrc + u * 8);
      const float* bsrc = Wsrc + (size_t)(nrow0 + rB) * Hdim + kt * 64 + kB;
      bf16_t* bdst = Bld + rB * 72 + kB;
      #pragma unroll
      for (int u = 0; u < 2; ++u)
        *reinterpret_cast<bf16x8*>(bdst + u * 8) = load_cvt8(bsrc + u * 8);
    }
    __syncthreads();
    #pragma unroll
    for (int ks = 0; ks < 2; ++ks){
      bf16x8 a[4], bb[2];
      #pragma unroll
      for (int mi = 0; mi < 4; ++mi)
        a[mi] = *reinterpret_cast<const bf16x8*>(&Ald[(wm * 64 + mi * 16 + lane16) * 72 + ks * 32 + grp * 8]);
      #pragma unroll
      for (int ni = 0; ni < 2; ++ni)
        bb[ni] = *reinterpret_cast<const bf16x8*>(&Bld[(wn * 32 + ni * 16 + lane16) * 72 + ks * 32 + grp * 8]);
      #pragma unroll
      for (int mi = 0; mi < 4; ++mi)
        #pragma unroll
        for (int ni = 0; ni < 2; ++ni)
          acc[mi][ni] = __builtin_amdgcn_mfma_f32_16x16x32_bf16(a[mi], bb[ni], acc[mi][ni], 0, 0, 0);
    }
    __syncthreads();
  }

  #pragma unroll
  for (int mi = 0; mi < 4; ++mi){
    #pragma unroll
    for (int ni = 0; ni < 2; ++ni){
      #pragma unroll
      for (int j = 0; j < 4; ++j){
        int m = m0 + wm * 64 + mi * 16 + grp * 4 + j;
        int dl = wn * 32 + ni * 16 + lane16;
        int b = m >> 11;
        int s = m & 2047;
        bf16_t v = (bf16_t)acc[mi][ni][j];
        if (nt < 9)
          qbuf[(((size_t)b * NH + nt) * Slen + s) * HD + dl] = v;
        else if (nt < 12)
          kbuf[(((size_t)b * NKV + (nt - 9)) * Slen + s) * HD + dl] = v;
        else
          vtbuf[(((size_t)b * NKV + (nt - 12)) * HD + dl) * Slen + s] = v;
      }
    }
  }
}

// ---------------- RoPE in-place on q+k (contiguous) ----------------
__global__ void rope_apply_all(bf16_t* __restrict__ qkbuf, const int* __restrict__ pos_ids,
                               const float* __restrict__ cost, const float* __restrict__ sint,
                               float qscale)
{
  int idx = blockIdx.x * blockDim.x + threadIdx.x;
  const int qrows = Bsz * NH * Slen;
  const int total = qrows + Bsz * NKV * Slen;
  if (idx >= total) return;
  const bool isq = idx < qrows;
  int s = idx & (Slen - 1);
  int b = isq ? idx / (NH * Slen) : (idx - qrows) / (NKV * Slen);
  float scale = isq ? qscale : 1.0f;
  bf16_t* row = qkbuf + (size_t)idx * HD;
  int pos = pos_ids[b * Slen + s];
  const float* cp = cost + (size_t)pos * 32;
  const float* sp = sint + (size_t)pos * 32;
  float x[64];
  #pragma unroll
  for (int v = 0; v < 8; ++v){
    bf16x8 t8 = *reinterpret_cast<const bf16x8*>(row + v * 8);
    #pragma unroll
    for (int i = 0; i < 8; ++i) x[v * 8 + i] = (float)t8[i];
  }
  bf16_t o[64];
  #pragma unroll
  for (int j = 0; j < 32; ++j){
    float c = cp[j], sn = sp[j];
    o[j]      = (bf16_t)((x[j] * c - x[j + 32] * sn) * scale);
    o[j + 32] = (bf16_t)((x[j + 32] * c + x[j] * sn) * scale);
  }
  #pragma unroll
  for (int v = 0; v < 8; ++v)
    *reinterpret_cast<bf16x8*>(row + v * 8) = *reinterpret_cast<bf16x8*>(o + v * 8);
}

// ---------------- Flash attention v5b: barrier-free, 2 independent waves/block ----------------
// Wave = 32 q-rows, KV tiles of 32, per-wave dbuf LDS, counted-vmcnt pipeline, no __syncthreads.
// STAGE = 4 K-loads then 4 V-loads (8 x 1KB). Steady-state waits: vmcnt(4)=K ready, vmcnt(8)=V ready.
__launch_bounds__(128)
__global__ void flash_attn_kernel(const bf16_t* __restrict__ qbuf,
                                  const bf16_t* __restrict__ kbuf,
                                  const bf16_t* __restrict__ vtbuf,
                                  bf16_t* __restrict__ attn_out)
{
  __shared__ bf16_t Kld[2][2][32 * 64];   // [wave][dbuf][k-row][d]
  __shared__ bf16_t Vld[2][2][64 * 32];   // [wave][dbuf][d-row][k]
  const int t = threadIdx.x, l = t & 63, w = t >> 6;
  const int l32 = l & 31, hi = l >> 5;

  // XCD-chunked: 1152 blocks = 8 chunks of 144 (4.5 bh per XCD)
  const int flat = blockIdx.x;
  const int v = (flat & 7) * 144 + (flat >> 3);
  const int bh = v >> 5;
  const int p  = v & 31;
  const int jq = w ? (63 - p) : p;        // wave-complementary => constant block work (65 tiles)
  const int b = bh / NH, h = bh % NH, kvh = h / (NH / NKV);

  const bf16_t* qp = qbuf + ((size_t)b * NH + h) * Slen * HD;
  const bf16_t* kp = kbuf + ((size_t)b * NKV + kvh) * Slen * HD;
  const bf16_t* vp = vtbuf + ((size_t)b * NKV + kvh) * HD * Slen;

  // staging lane geometry (pre-swizzled global source, linear LDS dest)
  const int krow = l >> 3;                     // 0..7
  const int ksc  = ((l & 7) ^ krow) * 8;       // K src col (elems): Kld[r][c]=K[r][c^(r&7)]
  const int vrow = l >> 2;                     // 0..15
  const int vsc  = ((l & 3) ^ (vrow & 3)) * 8; // V src col (elems): Vld[d][c]=V[d][c^(d&3)]

  auto STAGE = [&](int kt, int buf){
    const int k0 = kt * 32;
    #pragma unroll
    for (int u = 0; u < 4; ++u)                // 4 x 1KB: k-rows u*8+krow (0..31)
      gload16(kp + (size_t)(k0 + u * 8 + krow) * HD + ksc, &Kld[w][buf][u * 512]);
    #pragma unroll
    for (int u = 0; u < 4; ++u)                // 4 x 1KB: d-rows u*16+vrow (0..63)
      gload16(vp + (size_t)(u * 16 + vrow) * Slen + k0 + vsc, &Vld[w][buf][u * 512]);
  };

  const int ntiles = jq + 1;
  STAGE(0, 0);                                  // oldest 8 in vmcnt queue

  const int q0 = jq * 32;
  bf16x8 aq[4];                                 // Q[q0+l32][ds*16+hi*8 ..]
  #pragma unroll
  for (int ds = 0; ds < 4; ++ds)
    aq[ds] = *reinterpret_cast<const bf16x8*>(qp + (size_t)(q0 + l32) * HD + ds * 16 + hi * 8);

  f32x16 acco[2];                               // O^T[d = db*32 + crow(r,hi)][q=l32]
  #pragma unroll
  for (int db = 0; db < 2; ++db)
    #pragma unroll
    for (int r = 0; r < 16; ++r) acco[db][r] = 0.f;
  float mrun = -1e30f, lrun = 0.f;

  for (int kt = 0; kt < ntiles; ++kt){
    const int cur = kt & 1;
    const bf16_t* Kc = &Kld[w][cur][0];
    const bf16_t* Vc = &Vld[w][cur][0];

    // K(kt) staged: everything older than the 4 V-loads of this tile is retired
    asm volatile("s_waitcnt vmcnt(4)" ::: "memory");

    // ---- QK^T swapped: sacc[r] = S^T[k = crow(r,hi)][q = l32] ----
    f32x16 sacc;
    #pragma unroll
    for (int r = 0; r < 16; ++r) sacc[r] = 0.f;
    __builtin_amdgcn_s_setprio(1);
    #pragma unroll
    for (int ds = 0; ds < 4; ++ds){
      bf16x8 ak = *reinterpret_cast<const bf16x8*>(
          &Kc[l32 * 64 + (((ds * 2 + hi) ^ (l32 & 7)) * 8)]);
      sacc = __builtin_amdgcn_mfma_f32_32x32x16_bf16(ak, aq[ds], sacc, 0, 0, 0);
    }
    __builtin_amdgcn_s_setprio(0);

    const bool last = (kt + 1 == ntiles);
    if (!last) STAGE(kt + 1, cur ^ 1);          // overlaps softmax below

    // ---- causal mask (diag tile only) ----
    if (kt == jq){
      #pragma unroll
      for (int r = 0; r < 16; ++r){
        int crow = (r & 3) + 8 * (r >> 2) + 4 * hi;
        if (crow > l32) sacc[r] = -1e30f;
      }
    }

    // ---- row max: in-lane tree + 1 cross-lane ----
    float tmax = fmaxf(sacc[0], sacc[1]);
    #pragma unroll
    for (int r = 2; r < 16; ++r) tmax = fmaxf(tmax, sacc[r]);
    tmax = fmaxf(tmax, __shfl_xor(tmax, 32, 64));

    // ---- defer-max (THR=8, log2 domain) ----
    if (__ballot(tmax - mrun > 8.f)){
      float mnew = fmaxf(mrun, tmax);
      float sf = __builtin_amdgcn_exp2f(mrun - mnew);
      lrun *= sf;
      #pragma unroll
      for (int db = 0; db < 2; ++db)
        #pragma unroll
        for (int r = 0; r < 16; ++r) acco[db][r] *= sf;
      mrun = mnew;
    }

    // ---- exp2 + row sum ----
    float rsum = 0.f;
    #pragma unroll
    for (int r = 0; r < 16; ++r){
      float pv = __builtin_amdgcn_exp2f(sacc[r] - mrun);
      sacc[r] = pv;
      rsum += pv;
    }
    rsum += __shfl_xor(rsum, 32, 64);
    lrun += rsum;

    // ---- P -> bf16 B-fragments in-register ----
    u32 wv[8];
    #pragma unroll
    for (int j = 0; j < 8; ++j){
      float lo = sacc[2 * j], hp = sacc[2 * j + 1];
      asm("v_cvt_pk_bf16_f32 %0, %1, %2" : "=v"(wv[j]) : "v"(lo), "v"(hp));
    }
    asm volatile("v_permlane32_swap_b32 %0, %1" : "+v"(wv[0]), "+v"(wv[2]));
    asm volatile("v_permlane32_swap_b32 %0, %1" : "+v"(wv[1]), "+v"(wv[3]));
    asm volatile("v_permlane32_swap_b32 %0, %1" : "+v"(wv[4]), "+v"(wv[6]));
    asm volatile("v_permlane32_swap_b32 %0, %1" : "+v"(wv[5]), "+v"(wv[7]));
    u32x4 pa0 = (u32x4){wv[0], wv[1], wv[2], wv[3]};
    u32x4 pa1 = (u32x4){wv[4], wv[5], wv[6], wv[7]};

    // ---- wait V(kt): the 8 loads of tile kt+1 may stay in flight ----
    if (!last) asm volatile("s_waitcnt vmcnt(8)" ::: "memory");
    else       asm volatile("s_waitcnt vmcnt(0)" ::: "memory");

    // ---- PV swapped: acco[db] += mfma(V^T, P^T) ----
    __builtin_amdgcn_s_setprio(1);
    #pragma unroll
    for (int ks = 0; ks < 2; ++ks){
      #pragma unroll
      for (int db = 0; db < 2; ++db){
        bf16x8 av = *reinterpret_cast<const bf16x8*>(
            &Vc[(db * 32 + l32) * 32 + (((ks * 2 + hi) ^ (l32 & 3)) * 8)]);
        acco[db] = __builtin_amdgcn_mfma_f32_32x32x16_bf16(
            av, __builtin_bit_cast(bf16x8, ks ? pa1 : pa0), acco[db], 0, 0, 0);
      }
    }
    __builtin_amdgcn_s_setprio(0);
  }

  // ---- epilogue ----
  const float linv = 1.0f / lrun;
  const int srow = q0 + l32;
  bf16_t* orow = attn_out + ((size_t)b * Slen + srow) * (NH * HD) + h * HD;
  #pragma unroll
  for (int db = 0; db < 2; ++db){
    #pragma unroll
    for (int j = 0; j < 8; ++j){
      int r = 2 * j;
      int d = db * 32 + (r & 3) + 8 * (r >> 2) + 4 * hi;
      u32 pw;
      float lo = acco[db][r] * linv, hp = acco[db][r + 1] * linv;
      asm("v_cvt_pk_bf16_f32 %0, %1, %2" : "=v"(pw) : "v"(lo), "v"(hp));
      *reinterpret_cast<u32*>(orow + d) = pw;
    }
  }
}

// ---------------- Output GEMM: attn (8192x576 bf16) @ Wo^T -> fp32 ----------------
__launch_bounds__(256)
__global__ void out_gemm_kernel(const bf16_t* __restrict__ A,
                                const float* __restrict__ Wo,
                                float* __restrict__ out)
{
  __shared__ bf16_t Ald[128 * 72];
  __shared__ bf16_t Bld[64 * 72];
  const int t = threadIdx.x;
  const int l = t & 63;
  const int wid = t >> 6;
  const int wm = wid >> 1, wn = wid & 1;
  const int lane16 = l & 15, grp = l >> 4;
  const int m0 = blockIdx.x * 128;
  const int nt = blockIdx.y;

  const f32x4 fzero = {0.f, 0.f, 0.f, 0.f};
  f32x4 acc[4][2];
  #pragma unroll
  for (int mi = 0; mi < 4; ++mi)
    #pragma unroll
    for (int ni = 0; ni < 2; ++ni)
      acc[mi][ni] = fzero;

  const int rA = t >> 1, kA = (t & 1) * 32;
  const int rB = t >> 2, kB = (t & 3) * 16;

  for (int kt = 0; kt < 9; ++kt){
    {
      const bf16_t* asrc = A + (size_t)(m0 + rA) * Hdim + kt * 64 + kA;
      bf16_t* adst = Ald + rA * 72 + kA;
      #pragma unroll
      for (int u = 0; u < 4; ++u)
        *reinterpret_cast<bf16x8*>(adst + u * 8) = *reinterpret_cast<const bf16x8*>(asrc + u * 8);
      const float* bsrc = Wo + (size_t)(nt * 64 + rB) * Hdim + kt * 64 + kB;
      bf16_t* bdst = Bld + rB * 72 + kB;
      #pragma unroll
      for (int u = 0; u < 2; ++u)
        *reinterpret_cast<bf16x8*>(bdst + u * 8) = load_cvt8(bsrc + u * 8);
    }
    __syncthreads();
    #pragma unroll
    for (int ks = 0; ks < 2; ++ks){
      bf16x8 a[4], bb[2];
      #pragma unroll
      for (int mi = 0; mi < 4; ++mi)
        a[mi] = *reinterpret_cast<const bf16x8*>(&Ald[(wm * 64 + mi * 16 + lane16) * 72 + ks * 32 + grp * 8]);
      #pragma unroll
      for (int ni = 0; ni < 2; ++ni)
        bb[ni] = *reinterpret_cast<const bf16x8*>(&Bld[(wn * 32 + ni * 16 + lane16) * 72 + ks * 32 + grp * 8]);
      #pragma unroll
      for (int mi = 0; mi < 4; ++mi)
        #pragma unroll
        for (int ni = 0; ni < 2; ++ni)
          acc[mi][ni] = __builtin_amdgcn_mfma_f32_16x16x32_bf16(a[mi], bb[ni], acc[mi][ni], 0, 0, 0);
    }
    __syncthreads();
  }

  #pragma unroll
  for (int mi = 0; mi < 4; ++mi){
    #pragma unroll
    for (int ni = 0; ni < 2; ++ni){
      #pragma unroll
      for (int j = 0; j < 4; ++j){
        int m = m0 + wm * 64 + mi * 16 + grp * 4 + j;
        int n = nt * 64 + wn * 32 + ni * 16 + lane16;
        out[(size_t)m * Hdim + n] = acc[mi][ni][j];
      }
    }
  }
}

extern "C" void kernel_launch(void* const* d_in, const int* in_sizes, int n_in,
                              void* d_out, int out_size, void* d_ws, size_t ws_size,
                              hipStream_t stream) {
  const float* X   = (const float*)d_in[0];
  const int* pos   = (const int*)d_in[2];
  const float* Wq  = (const float*)d_in[3];
  const float* Wk  = (const float*)d_in[4];
  const float* Wv  = (const float*)d_in[5];
  const float* Wo  = (const float*)d_in[6];
  float* out = (float*)d_out;

  char* ws = (char*)d_ws;
  float* cost = (float*)ws;
  float* sint = (float*)(ws + (size_t)MAXPOS * 32 * 4);
  bf16_t* qb = (bf16_t*)(ws + 2 * (size_t)MAXPOS * 32 * 4);
  bf16_t* kb = qb + (size_t)Bsz * NH * Slen * HD;
  bf16_t* vt = kb + (size_t)Bsz * NKV * Slen * HD;
  bf16_t* ab = vt + (size_t)Bsz * NKV * Slen * HD;

  const float QSCALE = 0.125f * 1.44269504088896f;

  rope_table_kernel<<<dim3((Slen * 32 + 255) / 256), dim3(256), 0, stream>>>(cost, sint);
  qkv_gemm_kernel<<<dim3(64, 15), dim3(256), 0, stream>>>(X, Wq, Wk, Wv, qb, kb, vt);
  rope_apply_all<<<dim3((Bsz * (NH + NKV) * Slen + 255) / 256), dim3(256), 0, stream>>>(qb, pos, cost, sint, QSCALE);
  flash_attn_kernel<<<dim3(1152), dim3(128), 0, stream>>>(qb, kb, vt, ab);
  out_gemm_kernel<<<dim3(64, 9), dim3(256), 0, stream>>>(ab, Wo, out);
}

// Round 7
// 119.600 us; speedup vs baseline: 1.5290x; 1.5290x over previous
//
#include <hip/hip_runtime.h>
#include <hip/hip_bf16.h>
#include <math.h>

#define Bsz 4
#define Slen 2048
#define Hdim 576
#define NH 9
#define NKV 3
#define HD 64

typedef __bf16 bf16_t;
typedef __bf16 bf16x8 __attribute__((ext_vector_type(8)));
typedef float f32x4 __attribute__((ext_vector_type(4)));
typedef float f32x16 __attribute__((ext_vector_type(16)));
typedef unsigned int u32;
typedef unsigned int u32x4 __attribute__((ext_vector_type(4)));

static __device__ __forceinline__ bf16x8 load_cvt8(const float* __restrict__ src){
  float4 f0 = *reinterpret_cast<const float4*>(src);
  float4 f1 = *reinterpret_cast<const float4*>(src + 4);
  bf16x8 v;
  v[0]=(bf16_t)f0.x; v[1]=(bf16_t)f0.y; v[2]=(bf16_t)f0.z; v[3]=(bf16_t)f0.w;
  v[4]=(bf16_t)f1.x; v[5]=(bf16_t)f1.y; v[6]=(bf16_t)f1.z; v[7]=(bf16_t)f1.w;
  return v;
}

// async global->LDS, 16B per lane
static __device__ __forceinline__ void gload16(const bf16_t* g, bf16_t* l){
  __builtin_amdgcn_global_load_lds((const __attribute__((address_space(1))) void*)g,
                                   (__attribute__((address_space(3))) void*)l, 16, 0, 0);
}

// ---------------- RoPE tables (positions 0..Slen-1) ----------------
__global__ void rope_table_kernel(float* __restrict__ cost, float* __restrict__ sint){
  int i = blockIdx.x * blockDim.x + threadIdx.x;
  if (i >= Slen * 32) return;
  int j = i & 31;
  int p = i >> 5;
  double invf = pow(100000.0, -(double)j / 32.0);
  double ang = (double)p * invf;
  cost[i] = (float)cos(ang);
  sint[i] = (float)sin(ang);
}

// ---------------- Precast: X, Wq|Wk|Wv (concat rows), Wo -> bf16 ----------------
__global__ void precast_kernel(const float* __restrict__ X,
                               const float* __restrict__ Wq,
                               const float* __restrict__ Wk,
                               const float* __restrict__ Wv,
                               const float* __restrict__ Wo,
                               bf16_t* __restrict__ Xb,
                               bf16_t* __restrict__ Wb,
                               bf16_t* __restrict__ Wob)
{
  const int NX  = 8192 * 576 / 8;   // 589824 chunks of 8
  const int NWq = 576 * 576 / 8;    // 41472
  const int NWk = 192 * 576 / 8;    // 13824
  const int NWo = 576 * 576 / 8;    // 41472
  int i = blockIdx.x * blockDim.x + threadIdx.x;
  const int total = NX + NWq + 2 * NWk + NWo;
  if (i >= total) return;
  const float* src; bf16_t* dst; int off;
  if (i < NX)                    { src = X;  dst = Xb;            off = i; }
  else if (i < NX + NWq)         { src = Wq; dst = Wb;            off = i - NX; }
  else if (i < NX + NWq + NWk)   { src = Wk; dst = Wb + 331776;   off = i - NX - NWq; }
  else if (i < NX + NWq + 2*NWk) { src = Wv; dst = Wb + 442368;   off = i - NX - NWq - NWk; }
  else                           { src = Wo; dst = Wob;           off = i - NX - NWq - 2*NWk; }
  *reinterpret_cast<bf16x8*>(dst + (size_t)off * 8) = load_cvt8(src + (size_t)off * 8);
}

// ---------------- QKV projection GEMM v2 (M=8192, K=576, N=960), bf16 gload_lds dbuf ----------------
__launch_bounds__(256)
__global__ void qkv_gemm_kernel(const bf16_t* __restrict__ Xb,
                                const bf16_t* __restrict__ Wb,
                                bf16_t* __restrict__ qbuf,
                                bf16_t* __restrict__ kbuf,
                                bf16_t* __restrict__ vtbuf)
{
  __shared__ bf16_t Ald[2][128 * 64];
  __shared__ bf16_t Bld[2][64 * 64];
  const int t = threadIdx.x, l = t & 63, w = t >> 6;
  const int wm = w >> 1, wn = w & 1;
  const int lane16 = l & 15, grp = l >> 4;
  const int m0 = blockIdx.x * 128;
  const int nt = blockIdx.y;          // 0..14 -> rows nt*64 of Wb
  const int nrow0 = nt * 64;

  const int sr = l >> 3;              // 0..7
  const int sc = ((l & 7) ^ sr) * 8;  // pre-swizzled source col: lds[r][c]=G[r][c^(r&7)]

  f32x4 acc[4][2];
  #pragma unroll
  for (int mi = 0; mi < 4; ++mi)
    #pragma unroll
    for (int ni = 0; ni < 2; ++ni)
      acc[mi][ni] = (f32x4){0.f, 0.f, 0.f, 0.f};

  auto STAGE = [&](int kt, int buf){
    const int k0 = kt * 64;
    #pragma unroll
    for (int u = 0; u < 4; ++u)       // A tile 128x64: wave w rows w*32..w*32+31
      gload16(Xb + (size_t)(m0 + w * 32 + u * 8 + sr) * Hdim + k0 + sc,
              &Ald[buf][(w * 32 + u * 8) * 64]);
    #pragma unroll
    for (int u = 0; u < 2; ++u)       // B tile 64x64: wave w rows w*16..w*16+15
      gload16(Wb + (size_t)(nrow0 + w * 16 + u * 8 + sr) * Hdim + k0 + sc,
              &Bld[buf][(w * 16 + u * 8) * 64]);
  };

  STAGE(0, 0);
  asm volatile("s_waitcnt vmcnt(0)" ::: "memory");
  __syncthreads();

  const int sl7 = lane16 & 7;
  for (int kt = 0; kt < 9; ++kt){
    const int buf = kt & 1;
    if (kt + 1 < 9) STAGE(kt + 1, buf ^ 1);
    #pragma unroll
    for (int ks = 0; ks < 2; ++ks){
      bf16x8 a[4], bb[2];
      #pragma unroll
      for (int mi = 0; mi < 4; ++mi){
        int row = wm * 64 + mi * 16 + lane16;
        a[mi] = *reinterpret_cast<const bf16x8*>(&Ald[buf][row * 64 + (((ks * 4 + grp) ^ sl7) * 8)]);
      }
      #pragma unroll
      for (int ni = 0; ni < 2; ++ni){
        int row = wn * 32 + ni * 16 + lane16;
        bb[ni] = *reinterpret_cast<const bf16x8*>(&Bld[buf][row * 64 + (((ks * 4 + grp) ^ sl7) * 8)]);
      }
      #pragma unroll
      for (int mi = 0; mi < 4; ++mi)
        #pragma unroll
        for (int ni = 0; ni < 2; ++ni)
          acc[mi][ni] = __builtin_amdgcn_mfma_f32_16x16x32_bf16(a[mi], bb[ni], acc[mi][ni], 0, 0, 0);
    }
    if (kt + 1 < 9){
      asm volatile("s_waitcnt vmcnt(0)" ::: "memory");
      __syncthreads();
    }
  }

  #pragma unroll
  for (int mi = 0; mi < 4; ++mi){
    #pragma unroll
    for (int ni = 0; ni < 2; ++ni){
      #pragma unroll
      for (int j = 0; j < 4; ++j){
        int m = m0 + wm * 64 + mi * 16 + grp * 4 + j;
        int dl = wn * 32 + ni * 16 + lane16;
        int b = m >> 11;
        int s = m & 2047;
        bf16_t v = (bf16_t)acc[mi][ni][j];
        if (nt < 9)
          qbuf[(((size_t)b * NH + nt) * Slen + s) * HD + dl] = v;
        else if (nt < 12)
          kbuf[(((size_t)b * NKV + (nt - 9)) * Slen + s) * HD + dl] = v;
        else
          vtbuf[(((size_t)b * NKV + (nt - 12)) * HD + dl) * Slen + s] = v;
      }
    }
  }
}

// ---------------- RoPE in-place on q+k (contiguous) ----------------
__global__ void rope_apply_all(bf16_t* __restrict__ qkbuf, const int* __restrict__ pos_ids,
                               const float* __restrict__ cost, const float* __restrict__ sint,
                               float qscale)
{
  int idx = blockIdx.x * blockDim.x + threadIdx.x;
  const int qrows = Bsz * NH * Slen;
  const int total = qrows + Bsz * NKV * Slen;
  if (idx >= total) return;
  const bool isq = idx < qrows;
  int s = idx & (Slen - 1);
  int b = isq ? idx / (NH * Slen) : (idx - qrows) / (NKV * Slen);
  float scale = isq ? qscale : 1.0f;
  bf16_t* row = qkbuf + (size_t)idx * HD;
  int pos = pos_ids[b * Slen + s];
  const float* cp = cost + (size_t)pos * 32;
  const float* sp = sint + (size_t)pos * 32;
  float x[64];
  #pragma unroll
  for (int v = 0; v < 8; ++v){
    bf16x8 t8 = *reinterpret_cast<const bf16x8*>(row + v * 8);
    #pragma unroll
    for (int i = 0; i < 8; ++i) x[v * 8 + i] = (float)t8[i];
  }
  bf16_t o[64];
  #pragma unroll
  for (int j = 0; j < 32; ++j){
    float c = cp[j], sn = sp[j];
    o[j]      = (bf16_t)((x[j] * c - x[j + 32] * sn) * scale);
    o[j + 32] = (bf16_t)((x[j + 32] * c + x[j] * sn) * scale);
  }
  #pragma unroll
  for (int v = 0; v < 8; ++v)
    *reinterpret_cast<bf16x8*>(row + v * 8) = *reinterpret_cast<bf16x8*>(o + v * 8);
}

// ---------------- Flash attention (R4 verbatim): 32x32 swapped MFMA, reg-only P ----------------
__launch_bounds__(128)
__global__ void flash_attn_kernel(const bf16_t* __restrict__ qbuf,
                                  const bf16_t* __restrict__ kbuf,
                                  const bf16_t* __restrict__ vtbuf,
                                  bf16_t* __restrict__ attn_out)
{
  __shared__ bf16_t Kld[2][64 * 64];
  __shared__ bf16_t Vld[2][64 * 64];
  const int t = threadIdx.x, l = t & 63, w = t >> 6;     // w in 0..1
  const int l32 = l & 31, hi = l >> 5;

  // balanced schedule: same-CU (stride-256) blocks get alternating big/small qt
  const int flat = blockIdx.x;
  const int iq = flat / 36;
  const int bh = flat % 36;
  const int qt = (iq & 1) ? (iq >> 1) : (31 - (iq >> 1));
  const int b = bh / NH, h = bh % NH, kvh = h / (NH / NKV);

  const bf16_t* qp = qbuf + ((size_t)b * NH + h) * Slen * HD;
  const bf16_t* kp = kbuf + ((size_t)b * NKV + kvh) * Slen * HD;
  const bf16_t* vp = vtbuf + ((size_t)b * NKV + kvh) * HD * Slen;

  const int q0 = qt * 64 + w * 32;
  bf16x8 aq[4];
  #pragma unroll
  for (int ds = 0; ds < 4; ++ds)
    aq[ds] = *reinterpret_cast<const bf16x8*>(qp + (size_t)(q0 + l32) * HD + ds * 16 + hi * 8);

  f32x16 acco[2];   // O^T[d = db*32 + crow(r,hi)][q = l32]
  #pragma unroll
  for (int db = 0; db < 2; ++db)
    #pragma unroll
    for (int r = 0; r < 16; ++r) acco[db][r] = 0.f;
  float mrun = -1e30f, lrun = 0.f;

  const int sr = l >> 3;
  const int sc = ((l & 7) ^ sr) * 8;

  const int ntiles = qt + 1;
  int cur = 0;

  { // prologue: stage tile 0
    #pragma unroll
    for (int u = 0; u < 4; ++u){
      int r = (w * 4 + u) * 8 + sr;
      gload16(kp + (size_t)r * HD + sc, &Kld[0][(w * 4 + u) * 512]);
      gload16(vp + (size_t)r * Slen + sc, &Vld[0][(w * 4 + u) * 512]);
    }
  }
  asm volatile("s_waitcnt vmcnt(0)" ::: "memory");
  __syncthreads();

  for (int kb = 0; kb < ntiles; ++kb){
    if (kb + 1 < ntiles){
      const int k0_ = (kb + 1) * 64;
      #pragma unroll
      for (int u = 0; u < 4; ++u){
        int r = (w * 4 + u) * 8 + sr;
        gload16(kp + (size_t)(k0_ + r) * HD + sc, &Kld[cur ^ 1][(w * 4 + u) * 512]);
        gload16(vp + (size_t)r * Slen + k0_ + sc, &Vld[cur ^ 1][(w * 4 + u) * 512]);
      }
    }

    // ---- QK^T swapped: sacc[kb2] = S^T[k = kb2*32 + crow(r,hi)][q = l32] ----
    f32x16 sacc[2];
    #pragma unroll
    for (int kb2 = 0; kb2 < 2; ++kb2)
      #pragma unroll
      for (int r = 0; r < 16; ++r) sacc[kb2][r] = 0.f;

    __builtin_amdgcn_s_setprio(1);
    #pragma unroll
    for (int ds = 0; ds < 4; ++ds){
      #pragma unroll
      for (int kb2 = 0; kb2 < 2; ++kb2){
        int row = kb2 * 32 + l32;
        bf16x8 ak = *reinterpret_cast<const bf16x8*>(
            &Kld[cur][row * 64 + (((ds * 2 + hi) ^ (row & 7)) * 8)]);
        sacc[kb2] = __builtin_amdgcn_mfma_f32_32x32x16_bf16(ak, aq[ds], sacc[kb2], 0, 0, 0);
      }
    }
    __builtin_amdgcn_s_setprio(0);

    // ---- causal mask (diag tile only); crow(r,hi) = (r&3) + 8*(r>>2) + 4*hi ----
    if (kb == qt){
      const int q_wt = w * 32 + l32;
      #pragma unroll
      for (int kb2 = 0; kb2 < 2; ++kb2)
        #pragma unroll
        for (int r = 0; r < 16; ++r){
          int k_wt = kb2 * 32 + (r & 3) + 8 * (r >> 2) + 4 * hi;
          if (k_wt > q_wt) sacc[kb2][r] = -1e30f;
        }
    }

    // ---- row max: in-lane tree + 1 cross (lane pair l, l^32 shares q) ----
    float tmax;
    {
      float m0_ = fmaxf(sacc[0][0], sacc[0][1]);
      #pragma unroll
      for (int r = 2; r < 16; ++r) m0_ = fmaxf(m0_, sacc[0][r]);
      float m1_ = fmaxf(sacc[1][0], sacc[1][1]);
      #pragma unroll
      for (int r = 2; r < 16; ++r) m1_ = fmaxf(m1_, sacc[1][r]);
      tmax = fmaxf(m0_, m1_);
    }
    tmax = fmaxf(tmax, __shfl_xor(tmax, 32, 64));

    // ---- defer-max (THR = 8 in log2 domain) ----
    if (__ballot(tmax - mrun > 8.f)){
      float mnew = fmaxf(mrun, tmax);
      float sf = __builtin_amdgcn_exp2f(mrun - mnew);
      lrun *= sf;
      #pragma unroll
      for (int db = 0; db < 2; ++db)
        #pragma unroll
        for (int r = 0; r < 16; ++r) acco[db][r] *= sf;
      mrun = mnew;
    }

    // ---- exp2 + row sum ----
    float rs0 = 0.f, rs1 = 0.f;
    #pragma unroll
    for (int kb2 = 0; kb2 < 2; ++kb2){
      #pragma unroll
      for (int r = 0; r < 16; ++r){
        float p = __builtin_amdgcn_exp2f(sacc[kb2][r] - mrun);
        sacc[kb2][r] = p;
        if (kb2) rs1 += p; else rs0 += p;
      }
    }
    float rsum = rs0 + rs1;
    rsum += __shfl_xor(rsum, 32, 64);
    lrun += rsum;

    // ---- P -> bf16 PV fragments, in-register (cvt_pk + permlane32_swap) ----
    u32x4 pa[4];
    #pragma unroll
    for (int kb2 = 0; kb2 < 2; ++kb2){
      u32 wv[8];
      #pragma unroll
      for (int j = 0; j < 8; ++j){
        float lo = sacc[kb2][2 * j], hp = sacc[kb2][2 * j + 1];
        asm("v_cvt_pk_bf16_f32 %0, %1, %2" : "=v"(wv[j]) : "v"(lo), "v"(hp));
      }
      asm volatile("v_permlane32_swap_b32 %0, %1" : "+v"(wv[0]), "+v"(wv[2]));
      asm volatile("v_permlane32_swap_b32 %0, %1" : "+v"(wv[1]), "+v"(wv[3]));
      asm volatile("v_permlane32_swap_b32 %0, %1" : "+v"(wv[4]), "+v"(wv[6]));
      asm volatile("v_permlane32_swap_b32 %0, %1" : "+v"(wv[5]), "+v"(wv[7]));
      pa[2 * kb2]     = (u32x4){wv[0], wv[1], wv[2], wv[3]};
      pa[2 * kb2 + 1] = (u32x4){wv[4], wv[5], wv[6], wv[7]};
    }

    // ---- PV swapped: acco[db] += mfma(A = V^T, B = P^T) ----
    __builtin_amdgcn_s_setprio(1);
    #pragma unroll
    for (int ks = 0; ks < 4; ++ks){
      #pragma unroll
      for (int db = 0; db < 2; ++db){
        int row = db * 32 + l32;
        bf16x8 av = *reinterpret_cast<const bf16x8*>(
            &Vld[cur][row * 64 + (((ks * 2 + hi) ^ (row & 7)) * 8)]);
        acco[db] = __builtin_amdgcn_mfma_f32_32x32x16_bf16(
            av, __builtin_bit_cast(bf16x8, pa[ks]), acco[db], 0, 0, 0);
      }
    }
    __builtin_amdgcn_s_setprio(0);

    asm volatile("s_waitcnt vmcnt(0)" ::: "memory");
    __syncthreads();
    cur ^= 1;
  }

  // ---- epilogue ----
  const float linv = 1.0f / lrun;
  const int srow = q0 + l32;
  bf16_t* orow = attn_out + ((size_t)b * Slen + srow) * (NH * HD) + h * HD;
  #pragma unroll
  for (int db = 0; db < 2; ++db){
    #pragma unroll
    for (int j = 0; j < 8; ++j){
      int r = 2 * j;
      int d = db * 32 + (r & 3) + 8 * (r >> 2) + 4 * hi;
      u32 pw;
      float lo = acco[db][r] * linv, hp = acco[db][r + 1] * linv;
      asm("v_cvt_pk_bf16_f32 %0, %1, %2" : "=v"(pw) : "v"(lo), "v"(hp));
      *reinterpret_cast<u32*>(orow + d) = pw;
    }
  }
}

// ---------------- Output GEMM v2: ab (8192x576 bf16) @ Wob^T -> fp32, gload_lds dbuf ----------------
__launch_bounds__(256)
__global__ void out_gemm_kernel(const bf16_t* __restrict__ A,
                                const bf16_t* __restrict__ Wob,
                                float* __restrict__ out)
{
  __shared__ bf16_t Ald[2][128 * 64];
  __shared__ bf16_t Bld[2][64 * 64];
  const int t = threadIdx.x, l = t & 63, w = t >> 6;
  const int wm = w >> 1, wn = w & 1;
  const int lane16 = l & 15, grp = l >> 4;
  const int m0 = blockIdx.x * 128;
  const int nt = blockIdx.y;          // 0..8
  const int nrow0 = nt * 64;

  const int sr = l >> 3;
  const int sc = ((l & 7) ^ sr) * 8;

  f32x4 acc[4][2];
  #pragma unroll
  for (int mi = 0; mi < 4; ++mi)
    #pragma unroll
    for (int ni = 0; ni < 2; ++ni)
      acc[mi][ni] = (f32x4){0.f, 0.f, 0.f, 0.f};

  auto STAGE = [&](int kt, int buf){
    const int k0 = kt * 64;
    #pragma unroll
    for (int u = 0; u < 4; ++u)
      gload16(A + (size_t)(m0 + w * 32 + u * 8 + sr) * Hdim + k0 + sc,
              &Ald[buf][(w * 32 + u * 8) * 64]);
    #pragma unroll
    for (int u = 0; u < 2; ++u)
      gload16(Wob + (size_t)(nrow0 + w * 16 + u * 8 + sr) * Hdim + k0 + sc,
              &Bld[buf][(w * 16 + u * 8) * 64]);
  };

  STAGE(0, 0);
  asm volatile("s_waitcnt vmcnt(0)" ::: "memory");
  __syncthreads();

  const int sl7 = lane16 & 7;
  for (int kt = 0; kt < 9; ++kt){
    const int buf = kt & 1;
    if (kt + 1 < 9) STAGE(kt + 1, buf ^ 1);
    #pragma unroll
    for (int ks = 0; ks < 2; ++ks){
      bf16x8 a[4], bb[2];
      #pragma unroll
      for (int mi = 0; mi < 4; ++mi){
        int row = wm * 64 + mi * 16 + lane16;
        a[mi] = *reinterpret_cast<const bf16x8*>(&Ald[buf][row * 64 + (((ks * 4 + grp) ^ sl7) * 8)]);
      }
      #pragma unroll
      for (int ni = 0; ni < 2; ++ni){
        int row = wn * 32 + ni * 16 + lane16;
        bb[ni] = *reinterpret_cast<const bf16x8*>(&Bld[buf][row * 64 + (((ks * 4 + grp) ^ sl7) * 8)]);
      }
      #pragma unroll
      for (int mi = 0; mi < 4; ++mi)
        #pragma unroll
        for (int ni = 0; ni < 2; ++ni)
          acc[mi][ni] = __builtin_amdgcn_mfma_f32_16x16x32_bf16(a[mi], bb[ni], acc[mi][ni], 0, 0, 0);
    }
    if (kt + 1 < 9){
      asm volatile("s_waitcnt vmcnt(0)" ::: "memory");
      __syncthreads();
    }
  }

  #pragma unroll
  for (int mi = 0; mi < 4; ++mi){
    #pragma unroll
    for (int ni = 0; ni < 2; ++ni){
      #pragma unroll
      for (int j = 0; j < 4; ++j){
        int m = m0 + wm * 64 + mi * 16 + grp * 4 + j;
        int n = nrow0 + wn * 32 + ni * 16 + lane16;
        out[(size_t)m * Hdim + n] = acc[mi][ni][j];
      }
    }
  }
}

extern "C" void kernel_launch(void* const* d_in, const int* in_sizes, int n_in,
                              void* d_out, int out_size, void* d_ws, size_t ws_size,
                              hipStream_t stream) {
  const float* X   = (const float*)d_in[0];
  const int* pos   = (const int*)d_in[2];
  const float* Wq  = (const float*)d_in[3];
  const float* Wk  = (const float*)d_in[4];
  const float* Wv  = (const float*)d_in[5];
  const float* Wo  = (const float*)d_in[6];
  float* out = (float*)d_out;

  char* ws = (char*)d_ws;
  float* cost = (float*)ws;                                      // 256 KB
  float* sint = (float*)(ws + 262144);                           // 256 KB
  bf16_t* qb  = (bf16_t*)(ws + 524288);                          // 9.44 MB
  bf16_t* kb  = qb + (size_t)Bsz * NH * Slen * HD;               // 3.15 MB
  bf16_t* vt  = kb + (size_t)Bsz * NKV * Slen * HD;              // 3.15 MB
  bf16_t* Xb  = vt + (size_t)Bsz * NKV * Slen * HD;              // 9.44 MB
  bf16_t* ab  = Xb;                                              // alias: Xb dead after qkv_gemm
  bf16_t* Wb  = Xb + (size_t)8192 * 576;                         // 1.11 MB (960x576)
  bf16_t* Wob = Wb + (size_t)960 * 576;                          // 0.66 MB

  const float QSCALE = 0.125f * 1.44269504088896f;

  rope_table_kernel<<<dim3((Slen * 32 + 255) / 256), dim3(256), 0, stream>>>(cost, sint);
  precast_kernel<<<dim3(2736), dim3(256), 0, stream>>>(X, Wq, Wk, Wv, Wo, Xb, Wb, Wob);
  qkv_gemm_kernel<<<dim3(64, 15), dim3(256), 0, stream>>>(Xb, Wb, qb, kb, vt);
  rope_apply_all<<<dim3((Bsz * (NH + NKV) * Slen + 255) / 256), dim3(256), 0, stream>>>(qb, pos, cost, sint, QSCALE);
  flash_attn_kernel<<<dim3(1152), dim3(128), 0, stream>>>(qb, kb, vt, ab);
  out_gemm_kernel<<<dim3(64, 9), dim3(256), 0, stream>>>(ab, Wob, out);
}

// Round 8
// 119.374 us; speedup vs baseline: 1.5319x; 1.0019x over previous
//
#include <hip/hip_runtime.h>
#include <hip/hip_bf16.h>
#include <math.h>

#define Bsz 4
#define Slen 2048
#define Hdim 576
#define NH 9
#define NKV 3
#define HD 64

typedef __bf16 bf16_t;
typedef __bf16 bf16x8 __attribute__((ext_vector_type(8)));
typedef float f32x4 __attribute__((ext_vector_type(4)));
typedef float f32x16 __attribute__((ext_vector_type(16)));
typedef unsigned int u32;
typedef unsigned int u32x4 __attribute__((ext_vector_type(4)));

static __device__ __forceinline__ bf16x8 load_cvt8(const float* __restrict__ src){
  float4 f0 = *reinterpret_cast<const float4*>(src);
  float4 f1 = *reinterpret_cast<const float4*>(src + 4);
  bf16x8 v;
  v[0]=(bf16_t)f0.x; v[1]=(bf16_t)f0.y; v[2]=(bf16_t)f0.z; v[3]=(bf16_t)f0.w;
  v[4]=(bf16_t)f1.x; v[5]=(bf16_t)f1.y; v[6]=(bf16_t)f1.z; v[7]=(bf16_t)f1.w;
  return v;
}

// async global->LDS, 16B per lane
static __device__ __forceinline__ void gload16(const bf16_t* g, bf16_t* l){
  __builtin_amdgcn_global_load_lds((const __attribute__((address_space(1))) void*)g,
                                   (__attribute__((address_space(3))) void*)l, 16, 0, 0);
}

// ---------------- RoPE tables (positions 0..Slen-1) ----------------
__global__ void rope_table_kernel(float* __restrict__ cost, float* __restrict__ sint){
  int i = blockIdx.x * blockDim.x + threadIdx.x;
  if (i >= Slen * 32) return;
  int j = i & 31;
  int p = i >> 5;
  double invf = pow(100000.0, -(double)j / 32.0);
  double ang = (double)p * invf;
  cost[i] = (float)cos(ang);
  sint[i] = (float)sin(ang);
}

// ---------------- Precast: X, Wq|Wk|Wv (concat rows), Wo -> bf16 ----------------
__global__ void precast_kernel(const float* __restrict__ X,
                               const float* __restrict__ Wq,
                               const float* __restrict__ Wk,
                               const float* __restrict__ Wv,
                               const float* __restrict__ Wo,
                               bf16_t* __restrict__ Xb,
                               bf16_t* __restrict__ Wb,
                               bf16_t* __restrict__ Wob)
{
  const int NX  = 8192 * 576 / 8;
  const int NWq = 576 * 576 / 8;
  const int NWk = 192 * 576 / 8;
  int i = blockIdx.x * blockDim.x + threadIdx.x;
  const int total = NX + NWq + 2 * NWk + NWq;
  if (i >= total) return;
  const float* src; bf16_t* dst; int off;
  if (i < NX)                    { src = X;  dst = Xb;            off = i; }
  else if (i < NX + NWq)         { src = Wq; dst = Wb;            off = i - NX; }
  else if (i < NX + NWq + NWk)   { src = Wk; dst = Wb + 331776;   off = i - NX - NWq; }
  else if (i < NX + NWq + 2*NWk) { src = Wv; dst = Wb + 442368;   off = i - NX - NWq - NWk; }
  else                           { src = Wo; dst = Wob;           off = i - NX - NWq - 2*NWk; }
  *reinterpret_cast<bf16x8*>(dst + (size_t)off * 8) = load_cvt8(src + (size_t)off * 8);
}

// ---------------- QKV projection GEMM v2 (M=8192, K=576, N=960), bf16 gload_lds dbuf ----------------
__launch_bounds__(256)
__global__ void qkv_gemm_kernel(const bf16_t* __restrict__ Xb,
                                const bf16_t* __restrict__ Wb,
                                bf16_t* __restrict__ qbuf,
                                bf16_t* __restrict__ kbuf,
                                bf16_t* __restrict__ vtbuf)
{
  __shared__ bf16_t Ald[2][128 * 64];
  __shared__ bf16_t Bld[2][64 * 64];
  const int t = threadIdx.x, l = t & 63, w = t >> 6;
  const int wm = w >> 1, wn = w & 1;
  const int lane16 = l & 15, grp = l >> 4;
  const int m0 = blockIdx.x * 128;
  const int nt = blockIdx.y;
  const int nrow0 = nt * 64;

  const int sr = l >> 3;
  const int sc = ((l & 7) ^ sr) * 8;

  f32x4 acc[4][2];
  #pragma unroll
  for (int mi = 0; mi < 4; ++mi)
    #pragma unroll
    for (int ni = 0; ni < 2; ++ni)
      acc[mi][ni] = (f32x4){0.f, 0.f, 0.f, 0.f};

  auto STAGE = [&](int kt, int buf){
    const int k0 = kt * 64;
    #pragma unroll
    for (int u = 0; u < 4; ++u)
      gload16(Xb + (size_t)(m0 + w * 32 + u * 8 + sr) * Hdim + k0 + sc,
              &Ald[buf][(w * 32 + u * 8) * 64]);
    #pragma unroll
    for (int u = 0; u < 2; ++u)
      gload16(Wb + (size_t)(nrow0 + w * 16 + u * 8 + sr) * Hdim + k0 + sc,
              &Bld[buf][(w * 16 + u * 8) * 64]);
  };

  STAGE(0, 0);
  asm volatile("s_waitcnt vmcnt(0)" ::: "memory");
  __syncthreads();

  const int sl7 = lane16 & 7;
  for (int kt = 0; kt < 9; ++kt){
    const int buf = kt & 1;
    if (kt + 1 < 9) STAGE(kt + 1, buf ^ 1);
    #pragma unroll
    for (int ks = 0; ks < 2; ++ks){
      bf16x8 a[4], bb[2];
      #pragma unroll
      for (int mi = 0; mi < 4; ++mi){
        int row = wm * 64 + mi * 16 + lane16;
        a[mi] = *reinterpret_cast<const bf16x8*>(&Ald[buf][row * 64 + (((ks * 4 + grp) ^ sl7) * 8)]);
      }
      #pragma unroll
      for (int ni = 0; ni < 2; ++ni){
        int row = wn * 32 + ni * 16 + lane16;
        bb[ni] = *reinterpret_cast<const bf16x8*>(&Bld[buf][row * 64 + (((ks * 4 + grp) ^ sl7) * 8)]);
      }
      #pragma unroll
      for (int mi = 0; mi < 4; ++mi)
        #pragma unroll
        for (int ni = 0; ni < 2; ++ni)
          acc[mi][ni] = __builtin_amdgcn_mfma_f32_16x16x32_bf16(a[mi], bb[ni], acc[mi][ni], 0, 0, 0);
    }
    if (kt + 1 < 9){
      asm volatile("s_waitcnt vmcnt(0)" ::: "memory");
      __syncthreads();
    }
  }

  #pragma unroll
  for (int mi = 0; mi < 4; ++mi){
    #pragma unroll
    for (int ni = 0; ni < 2; ++ni){
      #pragma unroll
      for (int j = 0; j < 4; ++j){
        int m = m0 + wm * 64 + mi * 16 + grp * 4 + j;
        int dl = wn * 32 + ni * 16 + lane16;
        int b = m >> 11;
        int s = m & 2047;
        bf16_t v = (bf16_t)acc[mi][ni][j];
        if (nt < 9)
          qbuf[(((size_t)b * NH + nt) * Slen + s) * HD + dl] = v;
        else if (nt < 12)
          kbuf[(((size_t)b * NKV + (nt - 9)) * Slen + s) * HD + dl] = v;
        else
          vtbuf[(((size_t)b * NKV + (nt - 12)) * HD + dl) * Slen + s] = v;
      }
    }
  }
}

// ---------------- RoPE in-place on q+k (contiguous) ----------------
__global__ void rope_apply_all(bf16_t* __restrict__ qkbuf, const int* __restrict__ pos_ids,
                               const float* __restrict__ cost, const float* __restrict__ sint,
                               float qscale)
{
  int idx = blockIdx.x * blockDim.x + threadIdx.x;
  const int qrows = Bsz * NH * Slen;
  const int total = qrows + Bsz * NKV * Slen;
  if (idx >= total) return;
  const bool isq = idx < qrows;
  int s = idx & (Slen - 1);
  int b = isq ? idx / (NH * Slen) : (idx - qrows) / (NKV * Slen);
  float scale = isq ? qscale : 1.0f;
  bf16_t* row = qkbuf + (size_t)idx * HD;
  int pos = pos_ids[b * Slen + s];
  const float* cp = cost + (size_t)pos * 32;
  const float* sp = sint + (size_t)pos * 32;
  float x[64];
  #pragma unroll
  for (int v = 0; v < 8; ++v){
    bf16x8 t8 = *reinterpret_cast<const bf16x8*>(row + v * 8);
    #pragma unroll
    for (int i = 0; i < 8; ++i) x[v * 8 + i] = (float)t8[i];
  }
  bf16_t o[64];
  #pragma unroll
  for (int j = 0; j < 32; ++j){
    float c = cp[j], sn = sp[j];
    o[j]      = (bf16_t)((x[j] * c - x[j + 32] * sn) * scale);
    o[j + 32] = (bf16_t)((x[j + 32] * c + x[j] * sn) * scale);
  }
  #pragma unroll
  for (int v = 0; v < 8; ++v)
    *reinterpret_cast<bf16x8*>(row + v * 8) = *reinterpret_cast<bf16x8*>(o + v * 8);
}

// ---------------- Flash attention v6: split-K (flash-decoding) over KV range ----------------
// Block = 64 q-rows (2 waves x 32), KV tile range [t0,t1). qt<16: direct. qt>=16: two segments
// (tiles 0..15 / 16..qt) -> partials (packed-bf16 O^T, fp32 m/l) merged by combine_kernel.
__launch_bounds__(128)
__global__ void flash_attn_kernel(const bf16_t* __restrict__ qbuf,
                                  const bf16_t* __restrict__ kbuf,
                                  const bf16_t* __restrict__ vtbuf,
                                  bf16_t* __restrict__ attn_out,
                                  u32* __restrict__ part_O,
                                  float* __restrict__ part_ml)
{
  __shared__ bf16_t Kld[2][64 * 64];
  __shared__ bf16_t Vld[2][64 * 64];
  const int t = threadIdx.x, l = t & 63, w = t >> 6;
  const int l32 = l & 31, hi = l >> 5;

  // heavy-first schedule: v<16 -> seg0 (16 tiles); then (direct qt 15..0) x (seg1 qt 31..16)
  const int flat = blockIdx.x;
  const int v = flat / 36;
  const int bh = flat % 36;
  int qt, t0, t1, seg;
  if (v < 16){ qt = 16 + v; t0 = 0; t1 = 16; seg = 0; }
  else {
    int i = (v - 16) >> 1;
    if (((v - 16) & 1) == 0){ qt = 15 - i; t0 = 0; t1 = qt + 1; seg = -1; }
    else                    { qt = 31 - i; t0 = 16; t1 = qt + 1; seg = 1; }
  }
  const int b = bh / NH, h = bh % NH, kvh = h / (NH / NKV);

  const bf16_t* qp = qbuf + ((size_t)b * NH + h) * Slen * HD;
  const bf16_t* kp = kbuf + ((size_t)b * NKV + kvh) * Slen * HD;
  const bf16_t* vp = vtbuf + ((size_t)b * NKV + kvh) * HD * Slen;

  const int q0 = qt * 64 + w * 32;
  bf16x8 aq[4];
  #pragma unroll
  for (int ds = 0; ds < 4; ++ds)
    aq[ds] = *reinterpret_cast<const bf16x8*>(qp + (size_t)(q0 + l32) * HD + ds * 16 + hi * 8);

  f32x16 acco[2];   // O^T[d = db*32 + crow(r,hi)][q = l32], unnormalized
  #pragma unroll
  for (int db = 0; db < 2; ++db)
    #pragma unroll
    for (int r = 0; r < 16; ++r) acco[db][r] = 0.f;
  float mrun = -1e30f, lrun = 0.f;

  const int sr = l >> 3;
  const int sc = ((l & 7) ^ sr) * 8;

  auto STAGE = [&](int kt, int buf){
    const int k0 = kt * 64;
    #pragma unroll
    for (int u = 0; u < 4; ++u){
      int r = (w * 4 + u) * 8 + sr;
      gload16(kp + (size_t)(k0 + r) * HD + sc, &Kld[buf][(w * 4 + u) * 512]);
      gload16(vp + (size_t)r * Slen + k0 + sc, &Vld[buf][(w * 4 + u) * 512]);
    }
  };

  int cur = 0;
  STAGE(t0, 0);
  asm volatile("s_waitcnt vmcnt(0)" ::: "memory");
  __syncthreads();

  for (int kb = t0; kb < t1; ++kb){
    if (kb + 1 < t1) STAGE(kb + 1, cur ^ 1);

    // ---- QK^T swapped: sacc[kb2] = S^T[k = kb2*32 + crow(r,hi)][q = l32] ----
    f32x16 sacc[2];
    #pragma unroll
    for (int kb2 = 0; kb2 < 2; ++kb2)
      #pragma unroll
      for (int r = 0; r < 16; ++r) sacc[kb2][r] = 0.f;

    __builtin_amdgcn_s_setprio(1);
    #pragma unroll
    for (int ds = 0; ds < 4; ++ds){
      #pragma unroll
      for (int kb2 = 0; kb2 < 2; ++kb2){
        int row = kb2 * 32 + l32;
        bf16x8 ak = *reinterpret_cast<const bf16x8*>(
            &Kld[cur][row * 64 + (((ds * 2 + hi) ^ (row & 7)) * 8)]);
        sacc[kb2] = __builtin_amdgcn_mfma_f32_32x32x16_bf16(ak, aq[ds], sacc[kb2], 0, 0, 0);
      }
    }
    __builtin_amdgcn_s_setprio(0);

    // ---- causal mask (diag tile only) ----
    if (kb == qt){
      const int q_wt = w * 32 + l32;
      #pragma unroll
      for (int kb2 = 0; kb2 < 2; ++kb2)
        #pragma unroll
        for (int r = 0; r < 16; ++r){
          int k_wt = kb2 * 32 + (r & 3) + 8 * (r >> 2) + 4 * hi;
          if (k_wt > q_wt) sacc[kb2][r] = -1e30f;
        }
    }

    // ---- row max ----
    float tmax;
    {
      float m0_ = fmaxf(sacc[0][0], sacc[0][1]);
      #pragma unroll
      for (int r = 2; r < 16; ++r) m0_ = fmaxf(m0_, sacc[0][r]);
      float m1_ = fmaxf(sacc[1][0], sacc[1][1]);
      #pragma unroll
      for (int r = 2; r < 16; ++r) m1_ = fmaxf(m1_, sacc[1][r]);
      tmax = fmaxf(m0_, m1_);
    }
    tmax = fmaxf(tmax, __shfl_xor(tmax, 32, 64));

    // ---- defer-max (THR=8, log2 domain) ----
    if (__ballot(tmax - mrun > 8.f)){
      float mnew = fmaxf(mrun, tmax);
      float sf = __builtin_amdgcn_exp2f(mrun - mnew);
      lrun *= sf;
      #pragma unroll
      for (int db = 0; db < 2; ++db)
        #pragma unroll
        for (int r = 0; r < 16; ++r) acco[db][r] *= sf;
      mrun = mnew;
    }

    // ---- exp2 + row sum ----
    float rs0 = 0.f, rs1 = 0.f;
    #pragma unroll
    for (int kb2 = 0; kb2 < 2; ++kb2){
      #pragma unroll
      for (int r = 0; r < 16; ++r){
        float p = __builtin_amdgcn_exp2f(sacc[kb2][r] - mrun);
        sacc[kb2][r] = p;
        if (kb2) rs1 += p; else rs0 += p;
      }
    }
    float rsum = rs0 + rs1;
    rsum += __shfl_xor(rsum, 32, 64);
    lrun += rsum;

    // ---- P -> bf16 PV fragments, in-register ----
    u32x4 pa[4];
    #pragma unroll
    for (int kb2 = 0; kb2 < 2; ++kb2){
      u32 wv[8];
      #pragma unroll
      for (int j = 0; j < 8; ++j){
        float lo = sacc[kb2][2 * j], hp = sacc[kb2][2 * j + 1];
        asm("v_cvt_pk_bf16_f32 %0, %1, %2" : "=v"(wv[j]) : "v"(lo), "v"(hp));
      }
      asm volatile("v_permlane32_swap_b32 %0, %1" : "+v"(wv[0]), "+v"(wv[2]));
      asm volatile("v_permlane32_swap_b32 %0, %1" : "+v"(wv[1]), "+v"(wv[3]));
      asm volatile("v_permlane32_swap_b32 %0, %1" : "+v"(wv[4]), "+v"(wv[6]));
      asm volatile("v_permlane32_swap_b32 %0, %1" : "+v"(wv[5]), "+v"(wv[7]));
      pa[2 * kb2]     = (u32x4){wv[0], wv[1], wv[2], wv[3]};
      pa[2 * kb2 + 1] = (u32x4){wv[4], wv[5], wv[6], wv[7]};
    }

    // ---- PV swapped ----
    __builtin_amdgcn_s_setprio(1);
    #pragma unroll
    for (int ks = 0; ks < 4; ++ks){
      #pragma unroll
      for (int db = 0; db < 2; ++db){
        int row = db * 32 + l32;
        bf16x8 av = *reinterpret_cast<const bf16x8*>(
            &Vld[cur][row * 64 + (((ks * 2 + hi) ^ (row & 7)) * 8)]);
        acco[db] = __builtin_amdgcn_mfma_f32_32x32x16_bf16(
            av, __builtin_bit_cast(bf16x8, pa[ks]), acco[db], 0, 0, 0);
      }
    }
    __builtin_amdgcn_s_setprio(0);

    asm volatile("s_waitcnt vmcnt(0)" ::: "memory");
    __syncthreads();
    cur ^= 1;
  }

  if (seg < 0){
    // ---- direct epilogue ----
    const float linv = 1.0f / lrun;
    const int srow = q0 + l32;
    bf16_t* orow = attn_out + ((size_t)b * Slen + srow) * (NH * HD) + h * HD;
    #pragma unroll
    for (int db = 0; db < 2; ++db){
      #pragma unroll
      for (int j = 0; j < 8; ++j){
        int r = 2 * j;
        int d = db * 32 + (r & 3) + 8 * (r >> 2) + 4 * hi;
        u32 pw;
        float lo = acco[db][r] * linv, hp = acco[db][r + 1] * linv;
        asm("v_cvt_pk_bf16_f32 %0, %1, %2" : "=v"(pw) : "v"(lo), "v"(hp));
        *reinterpret_cast<u32*>(orow + d) = pw;
      }
    }
  } else {
    // ---- partial epilogue: packed bf16 O^T pairs [d/2][q], fp32 m/l ----
    const int slot = (bh * 16 + (qt - 16)) * 2 + seg;
    u32* po = part_O + ((size_t)slot * 2 + w) * 1024;
    float* pml = part_ml + ((size_t)slot * 2 + w) * 64;
    #pragma unroll
    for (int db = 0; db < 2; ++db){
      #pragma unroll
      for (int j = 0; j < 8; ++j){
        int r = 2 * j;
        int d = db * 32 + (r & 3) + 8 * (r >> 2) + 4 * hi;   // even
        u32 pw;
        float lo = acco[db][r], hp = acco[db][r + 1];
        asm("v_cvt_pk_bf16_f32 %0, %1, %2" : "=v"(pw) : "v"(lo), "v"(hp));
        po[(d >> 1) * 32 + l32] = pw;
      }
    }
    if (hi == 0){ pml[l32] = mrun; pml[32 + l32] = lrun; }
  }
}

// ---------------- Combine: merge 2 segments per q-row (qt >= 16) ----------------
__launch_bounds__(128)
__global__ void combine_kernel(const u32* __restrict__ part_O,
                               const float* __restrict__ part_ml,
                               bf16_t* __restrict__ attn_out)
{
  const int idx = blockIdx.x;           // 0..575
  const int bh = idx % 36, qtm = idx / 36;
  const int qt = 16 + qtm;
  const int b = bh / NH, h = bh % NH;
  const int t = threadIdx.x;
  const int q = t & 31, wg = (t >> 5) & 1, half = t >> 6;
  const int slot0 = (bh * 16 + qtm) * 2;

  const float* pml0 = part_ml + ((size_t)(slot0 + 0) * 2 + wg) * 64;
  const float* pml1 = part_ml + ((size_t)(slot0 + 1) * 2 + wg) * 64;
  float m1 = pml0[q], l1 = pml0[32 + q];
  float m2 = pml1[q], l2 = pml1[32 + q];
  float m = fmaxf(m1, m2);
  float a1 = __builtin_amdgcn_exp2f(m1 - m);
  float a2 = __builtin_amdgcn_exp2f(m2 - m);
  float linv = 1.0f / (l1 * a1 + l2 * a2);
  a1 *= linv; a2 *= linv;

  const u32* po0 = part_O + ((size_t)(slot0 + 0) * 2 + wg) * 1024;
  const u32* po1 = part_O + ((size_t)(slot0 + 1) * 2 + wg) * 1024;
  const int s = qt * 64 + wg * 32 + q;
  bf16_t* orow = attn_out + ((size_t)b * Slen + s) * (NH * HD) + h * HD;

  #pragma unroll
  for (int u = 0; u < 16; ++u){
    int dp = half * 16 + u;
    u32 v1 = po0[dp * 32 + q], v2 = po1[dp * 32 + q];
    float lo = a1 * __builtin_bit_cast(float, v1 << 16)
             + a2 * __builtin_bit_cast(float, v2 << 16);
    float hv = a1 * __builtin_bit_cast(float, v1 & 0xffff0000u)
             + a2 * __builtin_bit_cast(float, v2 & 0xffff0000u);
    u32 pw;
    asm("v_cvt_pk_bf16_f32 %0, %1, %2" : "=v"(pw) : "v"(lo), "v"(hv));
    *reinterpret_cast<u32*>(orow + 2 * dp) = pw;
  }
}

// ---------------- Output GEMM v2: ab (8192x576 bf16) @ Wob^T -> fp32, gload_lds dbuf ----------------
__launch_bounds__(256)
__global__ void out_gemm_kernel(const bf16_t* __restrict__ A,
                                const bf16_t* __restrict__ Wob,
                                float* __restrict__ out)
{
  __shared__ bf16_t Ald[2][128 * 64];
  __shared__ bf16_t Bld[2][64 * 64];
  const int t = threadIdx.x, l = t & 63, w = t >> 6;
  const int wm = w >> 1, wn = w & 1;
  const int lane16 = l & 15, grp = l >> 4;
  const int m0 = blockIdx.x * 128;
  const int nt = blockIdx.y;
  const int nrow0 = nt * 64;

  const int sr = l >> 3;
  const int sc = ((l & 7) ^ sr) * 8;

  f32x4 acc[4][2];
  #pragma unroll
  for (int mi = 0; mi < 4; ++mi)
    #pragma unroll
    for (int ni = 0; ni < 2; ++ni)
      acc[mi][ni] = (f32x4){0.f, 0.f, 0.f, 0.f};

  auto STAGE = [&](int kt, int buf){
    const int k0 = kt * 64;
    #pragma unroll
    for (int u = 0; u < 4; ++u)
      gload16(A + (size_t)(m0 + w * 32 + u * 8 + sr) * Hdim + k0 + sc,
              &Ald[buf][(w * 32 + u * 8) * 64]);
    #pragma unroll
    for (int u = 0; u < 2; ++u)
      gload16(Wob + (size_t)(nrow0 + w * 16 + u * 8 + sr) * Hdim + k0 + sc,
              &Bld[buf][(w * 16 + u * 8) * 64]);
  };

  STAGE(0, 0);
  asm volatile("s_waitcnt vmcnt(0)" ::: "memory");
  __syncthreads();

  const int sl7 = lane16 & 7;
  for (int kt = 0; kt < 9; ++kt){
    const int buf = kt & 1;
    if (kt + 1 < 9) STAGE(kt + 1, buf ^ 1);
    #pragma unroll
    for (int ks = 0; ks < 2; ++ks){
      bf16x8 a[4], bb[2];
      #pragma unroll
      for (int mi = 0; mi < 4; ++mi){
        int row = wm * 64 + mi * 16 + lane16;
        a[mi] = *reinterpret_cast<const bf16x8*>(&Ald[buf][row * 64 + (((ks * 4 + grp) ^ sl7) * 8)]);
      }
      #pragma unroll
      for (int ni = 0; ni < 2; ++ni){
        int row = wn * 32 + ni * 16 + lane16;
        bb[ni] = *reinterpret_cast<const bf16x8*>(&Bld[buf][row * 64 + (((ks * 4 + grp) ^ sl7) * 8)]);
      }
      #pragma unroll
      for (int mi = 0; mi < 4; ++mi)
        #pragma unroll
        for (int ni = 0; ni < 2; ++ni)
          acc[mi][ni] = __builtin_amdgcn_mfma_f32_16x16x32_bf16(a[mi], bb[ni], acc[mi][ni], 0, 0, 0);
    }
    if (kt + 1 < 9){
      asm volatile("s_waitcnt vmcnt(0)" ::: "memory");
      __syncthreads();
    }
  }

  #pragma unroll
  for (int mi = 0; mi < 4; ++mi){
    #pragma unroll
    for (int ni = 0; ni < 2; ++ni){
      #pragma unroll
      for (int j = 0; j < 4; ++j){
        int m = m0 + wm * 64 + mi * 16 + grp * 4 + j;
        int n = nrow0 + wn * 32 + ni * 16 + lane16;
        out[(size_t)m * Hdim + n] = acc[mi][ni][j];
      }
    }
  }
}

extern "C" void kernel_launch(void* const* d_in, const int* in_sizes, int n_in,
                              void* d_out, int out_size, void* d_ws, size_t ws_size,
                              hipStream_t stream) {
  const float* X   = (const float*)d_in[0];
  const int* pos   = (const int*)d_in[2];
  const float* Wq  = (const float*)d_in[3];
  const float* Wk  = (const float*)d_in[4];
  const float* Wv  = (const float*)d_in[5];
  const float* Wo  = (const float*)d_in[6];
  float* out = (float*)d_out;

  char* ws = (char*)d_ws;
  float* cost = (float*)ws;                                      // 256 KB
  float* sint = (float*)(ws + 262144);                           // 256 KB
  bf16_t* qb  = (bf16_t*)(ws + 524288);                          // 9.44 MB
  bf16_t* kb  = qb + (size_t)Bsz * NH * Slen * HD;               // 3.15 MB
  bf16_t* vt  = kb + (size_t)Bsz * NKV * Slen * HD;              // 3.15 MB
  bf16_t* Xb  = vt + (size_t)Bsz * NKV * Slen * HD;              // 9.44 MB
  bf16_t* ab  = Xb;                                              // alias: Xb dead after qkv_gemm
  bf16_t* Wb  = Xb + (size_t)8192 * 576;                         // 1.11 MB
  bf16_t* Wob = Wb + (size_t)960 * 576;                          // 0.66 MB
  u32*  part_O  = (u32*)(Wob + (size_t)576 * 576);               // 9.44 MB (1152 slots x 2 waves x 1024 u32)
  float* part_ml = (float*)(part_O + (size_t)1152 * 2 * 1024);   // 0.59 MB

  const float QSCALE = 0.125f * 1.44269504088896f;

  rope_table_kernel<<<dim3((Slen * 32 + 255) / 256), dim3(256), 0, stream>>>(cost, sint);
  precast_kernel<<<dim3(2736), dim3(256), 0, stream>>>(X, Wq, Wk, Wv, Wo, Xb, Wb, Wob);
  qkv_gemm_kernel<<<dim3(64, 15), dim3(256), 0, stream>>>(Xb, Wb, qb, kb, vt);
  rope_apply_all<<<dim3((Bsz * (NH + NKV) * Slen + 255) / 256), dim3(256), 0, stream>>>(qb, pos, cost, sint, QSCALE);
  flash_attn_kernel<<<dim3(1728), dim3(128), 0, stream>>>(qb, kb, vt, ab, part_O, part_ml);
  combine_kernel<<<dim3(576), dim3(128), 0, stream>>>(part_O, part_ml, ab);
  out_gemm_kernel<<<dim3(64, 9), dim3(256), 0, stream>>>(ab, Wob, out);
}

// Round 9
// 118.929 us; speedup vs baseline: 1.5376x; 1.0037x over previous
//
#include <hip/hip_runtime.h>
#include <hip/hip_bf16.h>
#include <math.h>

#define Bsz 4
#define Slen 2048
#define Hdim 576
#define NH 9
#define NKV 3
#define HD 64

typedef __bf16 bf16_t;
typedef __bf16 bf16x8 __attribute__((ext_vector_type(8)));
typedef float f32x4 __attribute__((ext_vector_type(4)));
typedef float f32x16 __attribute__((ext_vector_type(16)));
typedef unsigned int u32;
typedef unsigned int u32x4 __attribute__((ext_vector_type(4)));

static __device__ __forceinline__ bf16x8 load_cvt8(const float* __restrict__ src){
  float4 f0 = *reinterpret_cast<const float4*>(src);
  float4 f1 = *reinterpret_cast<const float4*>(src + 4);
  bf16x8 v;
  v[0]=(bf16_t)f0.x; v[1]=(bf16_t)f0.y; v[2]=(bf16_t)f0.z; v[3]=(bf16_t)f0.w;
  v[4]=(bf16_t)f1.x; v[5]=(bf16_t)f1.y; v[6]=(bf16_t)f1.z; v[7]=(bf16_t)f1.w;
  return v;
}

// async global->LDS, 16B per lane
static __device__ __forceinline__ void gload16(const bf16_t* g, bf16_t* l){
  __builtin_amdgcn_global_load_lds((const __attribute__((address_space(1))) void*)g,
                                   (__attribute__((address_space(3))) void*)l, 16, 0, 0);
}

// ---------------- RoPE tables (positions 0..Slen-1) ----------------
__global__ void rope_table_kernel(float* __restrict__ cost, float* __restrict__ sint){
  int i = blockIdx.x * blockDim.x + threadIdx.x;
  if (i >= Slen * 32) return;
  int j = i & 31;
  int p = i >> 5;
  double invf = pow(100000.0, -(double)j / 32.0);
  double ang = (double)p * invf;
  cost[i] = (float)cos(ang);
  sint[i] = (float)sin(ang);
}

// ---------------- Precast: X, Wq|Wk|Wv (concat rows), Wo -> bf16 ----------------
__global__ void precast_kernel(const float* __restrict__ X,
                               const float* __restrict__ Wq,
                               const float* __restrict__ Wk,
                               const float* __restrict__ Wv,
                               const float* __restrict__ Wo,
                               bf16_t* __restrict__ Xb,
                               bf16_t* __restrict__ Wb,
                               bf16_t* __restrict__ Wob)
{
  const int NX  = 8192 * 576 / 8;
  const int NWq = 576 * 576 / 8;
  const int NWk = 192 * 576 / 8;
  int i = blockIdx.x * blockDim.x + threadIdx.x;
  const int total = NX + NWq + 2 * NWk + NWq;
  if (i >= total) return;
  const float* src; bf16_t* dst; int off;
  if (i < NX)                    { src = X;  dst = Xb;            off = i; }
  else if (i < NX + NWq)         { src = Wq; dst = Wb;            off = i - NX; }
  else if (i < NX + NWq + NWk)   { src = Wk; dst = Wb + 331776;   off = i - NX - NWq; }
  else if (i < NX + NWq + 2*NWk) { src = Wv; dst = Wb + 442368;   off = i - NX - NWq - NWk; }
  else                           { src = Wo; dst = Wob;           off = i - NX - NWq - 2*NWk; }
  *reinterpret_cast<bf16x8*>(dst + (size_t)off * 8) = load_cvt8(src + (size_t)off * 8);
}

// ---------------- QKV projection GEMM v2 (M=8192, K=576, N=960), bf16 gload_lds dbuf ----------------
__launch_bounds__(256)
__global__ void qkv_gemm_kernel(const bf16_t* __restrict__ Xb,
                                const bf16_t* __restrict__ Wb,
                                bf16_t* __restrict__ qbuf,
                                bf16_t* __restrict__ kbuf,
                                bf16_t* __restrict__ vtbuf)
{
  __shared__ bf16_t Ald[2][128 * 64];
  __shared__ bf16_t Bld[2][64 * 64];
  const int t = threadIdx.x, l = t & 63, w = t >> 6;
  const int wm = w >> 1, wn = w & 1;
  const int lane16 = l & 15, grp = l >> 4;
  const int m0 = blockIdx.x * 128;
  const int nt = blockIdx.y;
  const int nrow0 = nt * 64;

  const int sr = l >> 3;
  const int sc = ((l & 7) ^ sr) * 8;

  f32x4 acc[4][2];
  #pragma unroll
  for (int mi = 0; mi < 4; ++mi)
    #pragma unroll
    for (int ni = 0; ni < 2; ++ni)
      acc[mi][ni] = (f32x4){0.f, 0.f, 0.f, 0.f};

  auto STAGE = [&](int kt, int buf){
    const int k0 = kt * 64;
    #pragma unroll
    for (int u = 0; u < 4; ++u)
      gload16(Xb + (size_t)(m0 + w * 32 + u * 8 + sr) * Hdim + k0 + sc,
              &Ald[buf][(w * 32 + u * 8) * 64]);
    #pragma unroll
    for (int u = 0; u < 2; ++u)
      gload16(Wb + (size_t)(nrow0 + w * 16 + u * 8 + sr) * Hdim + k0 + sc,
              &Bld[buf][(w * 16 + u * 8) * 64]);
  };

  STAGE(0, 0);
  asm volatile("s_waitcnt vmcnt(0)" ::: "memory");
  __syncthreads();

  const int sl7 = lane16 & 7;
  for (int kt = 0; kt < 9; ++kt){
    const int buf = kt & 1;
    if (kt + 1 < 9) STAGE(kt + 1, buf ^ 1);
    #pragma unroll
    for (int ks = 0; ks < 2; ++ks){
      bf16x8 a[4], bb[2];
      #pragma unroll
      for (int mi = 0; mi < 4; ++mi){
        int row = wm * 64 + mi * 16 + lane16;
        a[mi] = *reinterpret_cast<const bf16x8*>(&Ald[buf][row * 64 + (((ks * 4 + grp) ^ sl7) * 8)]);
      }
      #pragma unroll
      for (int ni = 0; ni < 2; ++ni){
        int row = wn * 32 + ni * 16 + lane16;
        bb[ni] = *reinterpret_cast<const bf16x8*>(&Bld[buf][row * 64 + (((ks * 4 + grp) ^ sl7) * 8)]);
      }
      #pragma unroll
      for (int mi = 0; mi < 4; ++mi)
        #pragma unroll
        for (int ni = 0; ni < 2; ++ni)
          acc[mi][ni] = __builtin_amdgcn_mfma_f32_16x16x32_bf16(a[mi], bb[ni], acc[mi][ni], 0, 0, 0);
    }
    if (kt + 1 < 9){
      asm volatile("s_waitcnt vmcnt(0)" ::: "memory");
      __syncthreads();
    }
  }

  #pragma unroll
  for (int mi = 0; mi < 4; ++mi){
    #pragma unroll
    for (int ni = 0; ni < 2; ++ni){
      #pragma unroll
      for (int j = 0; j < 4; ++j){
        int m = m0 + wm * 64 + mi * 16 + grp * 4 + j;
        int dl = wn * 32 + ni * 16 + lane16;
        int b = m >> 11;
        int s = m & 2047;
        bf16_t v = (bf16_t)acc[mi][ni][j];
        if (nt < 9)
          qbuf[(((size_t)b * NH + nt) * Slen + s) * HD + dl] = v;
        else if (nt < 12)
          kbuf[(((size_t)b * NKV + (nt - 9)) * Slen + s) * HD + dl] = v;
        else
          vtbuf[(((size_t)b * NKV + (nt - 12)) * HD + dl) * Slen + s] = v;
      }
    }
  }
}

// ---------------- RoPE in-place on q+k (contiguous) ----------------
__global__ void rope_apply_all(bf16_t* __restrict__ qkbuf, const int* __restrict__ pos_ids,
                               const float* __restrict__ cost, const float* __restrict__ sint,
                               float qscale)
{
  int idx = blockIdx.x * blockDim.x + threadIdx.x;
  const int qrows = Bsz * NH * Slen;
  const int total = qrows + Bsz * NKV * Slen;
  if (idx >= total) return;
  const bool isq = idx < qrows;
  int s = idx & (Slen - 1);
  int b = isq ? idx / (NH * Slen) : (idx - qrows) / (NKV * Slen);
  float scale = isq ? qscale : 1.0f;
  bf16_t* row = qkbuf + (size_t)idx * HD;
  int pos = pos_ids[b * Slen + s];
  const float* cp = cost + (size_t)pos * 32;
  const float* sp = sint + (size_t)pos * 32;
  float x[64];
  #pragma unroll
  for (int v = 0; v < 8; ++v){
    bf16x8 t8 = *reinterpret_cast<const bf16x8*>(row + v * 8);
    #pragma unroll
    for (int i = 0; i < 8; ++i) x[v * 8 + i] = (float)t8[i];
  }
  bf16_t o[64];
  #pragma unroll
  for (int j = 0; j < 32; ++j){
    float c = cp[j], sn = sp[j];
    o[j]      = (bf16_t)((x[j] * c - x[j + 32] * sn) * scale);
    o[j + 32] = (bf16_t)((x[j + 32] * c + x[j] * sn) * scale);
  }
  #pragma unroll
  for (int v = 0; v < 8; ++v)
    *reinterpret_cast<bf16x8*>(row + v * 8) = *reinterpret_cast<bf16x8*>(o + v * 8);
}

// ---------------- Flash attention v7: split-K + KVBLK=32 (16KB LDS -> high occupancy cap) ----------------
// Block = 64 q-rows (2 waves x 32). KV tiles of 32 positions. qt<16 direct; qt>=16 two segments
// split at KV tile 32 -> partials merged by combine_kernel. One barrier per tile.
// Diagonal tile differs per wave (dt = 2qt+w); wave0's tile 2qt+1 is fully masked -> 'dead' skip.
__launch_bounds__(128)
__global__ void flash_attn_kernel(const bf16_t* __restrict__ qbuf,
                                  const bf16_t* __restrict__ kbuf,
                                  const bf16_t* __restrict__ vtbuf,
                                  bf16_t* __restrict__ attn_out,
                                  u32* __restrict__ part_O,
                                  float* __restrict__ part_ml)
{
  __shared__ bf16_t Kld[2][32 * 64];   // 4KB per buf
  __shared__ bf16_t Vld[2][64 * 32];   // 4KB per buf
  const int t = threadIdx.x, l = t & 63, w = t >> 6;
  const int l32 = l & 31, hi = l >> 5;

  // heavy-first: v<16 -> seg0 of qt=16+v (32 tiles); then (direct qt 15..0) x (seg1 qt 31..16)
  const int flat = blockIdx.x;
  const int v = flat / 36;
  const int bh = flat % 36;
  int qt, t0, t1, seg;
  if (v < 16){ qt = 16 + v; t0 = 0; t1 = 32; seg = 0; }
  else {
    int i = (v - 16) >> 1;
    if (((v - 16) & 1) == 0){ qt = 15 - i; t0 = 0; t1 = 2 * qt + 2; seg = -1; }
    else                    { qt = 31 - i; t0 = 32; t1 = 2 * qt + 2; seg = 1; }
  }
  const int b = bh / NH, h = bh % NH, kvh = h / (NH / NKV);

  const bf16_t* qp = qbuf + ((size_t)b * NH + h) * Slen * HD;
  const bf16_t* kp = kbuf + ((size_t)b * NKV + kvh) * Slen * HD;
  const bf16_t* vp = vtbuf + ((size_t)b * NKV + kvh) * HD * Slen;

  const int q0 = qt * 64 + w * 32;
  bf16x8 aq[4];
  #pragma unroll
  for (int ds = 0; ds < 4; ++ds)
    aq[ds] = *reinterpret_cast<const bf16x8*>(qp + (size_t)(q0 + l32) * HD + ds * 16 + hi * 8);

  f32x16 acco[2];   // O^T[d = db*32 + crow(r,hi)][q = l32], unnormalized
  #pragma unroll
  for (int db = 0; db < 2; ++db)
    #pragma unroll
    for (int r = 0; r < 16; ++r) acco[db][r] = 0.f;
  float mrun = -1e30f, lrun = 0.f;

  // staging lane geometry (pre-swizzled global source, linear LDS dest)
  const int krow = l >> 3;                      // 0..7
  const int ksc  = ((l & 7) ^ krow) * 8;        // Kld[r][c]=K[r][c^(r&7)], c in 16B chunks
  const int vrow = l >> 2;                      // 0..15
  const int vsc  = ((l & 3) ^ (vrow & 3)) * 8;  // Vld[d][c]=V[d][c^(d&3)]

  auto STAGE = [&](int kt, int buf){
    const int k0 = kt * 32;
    #pragma unroll
    for (int u = 0; u < 2; ++u){
      int ub = w * 2 + u;                        // 0..3
      gload16(kp + (size_t)(k0 + ub * 8 + krow) * HD + ksc, &Kld[buf][ub * 512]);
      gload16(vp + (size_t)(ub * 16 + vrow) * Slen + k0 + vsc, &Vld[buf][ub * 512]);
    }
  };

  int cur = 0;
  STAGE(t0, 0);
  asm volatile("s_waitcnt vmcnt(0)" ::: "memory");
  __syncthreads();

  const int dt = 2 * qt + w;                    // this wave's diagonal tile
  for (int kb = t0; kb < t1; ++kb){
    if (kb + 1 < t1) STAGE(kb + 1, cur ^ 1);

    if (kb <= dt){                              // wave-uniform; kb > dt is fully masked (wave0 tail)
      // ---- QK^T swapped: sacc[r] = S^T[k = crow(r,hi)][q = l32] ----
      f32x16 sacc;
      #pragma unroll
      for (int r = 0; r < 16; ++r) sacc[r] = 0.f;
      __builtin_amdgcn_s_setprio(1);
      #pragma unroll
      for (int ds = 0; ds < 4; ++ds){
        bf16x8 ak = *reinterpret_cast<const bf16x8*>(
            &Kld[cur][l32 * 64 + (((ds * 2 + hi) ^ (l32 & 7)) * 8)]);
        sacc = __builtin_amdgcn_mfma_f32_32x32x16_bf16(ak, aq[ds], sacc, 0, 0, 0);
      }
      __builtin_amdgcn_s_setprio(0);

      // ---- causal mask (diagonal tile only) ----
      if (kb == dt){
        #pragma unroll
        for (int r = 0; r < 16; ++r){
          int crow = (r & 3) + 8 * (r >> 2) + 4 * hi;
          if (crow > l32) sacc[r] = -1e30f;
        }
      }

      // ---- row max: in-lane tree + 1 cross-lane (l <-> l^32) ----
      float tmax = fmaxf(sacc[0], sacc[1]);
      #pragma unroll
      for (int r = 2; r < 16; ++r) tmax = fmaxf(tmax, sacc[r]);
      tmax = fmaxf(tmax, __shfl_xor(tmax, 32, 64));

      // ---- defer-max (THR=8, log2 domain) ----
      if (__ballot(tmax - mrun > 8.f)){
        float mnew = fmaxf(mrun, tmax);
        float sf = __builtin_amdgcn_exp2f(mrun - mnew);
        lrun *= sf;
        #pragma unroll
        for (int db = 0; db < 2; ++db)
          #pragma unroll
          for (int r = 0; r < 16; ++r) acco[db][r] *= sf;
        mrun = mnew;
      }

      // ---- exp2 + row sum ----
      float rsum = 0.f;
      #pragma unroll
      for (int r = 0; r < 16; ++r){
        float pv = __builtin_amdgcn_exp2f(sacc[r] - mrun);
        sacc[r] = pv;
        rsum += pv;
      }
      rsum += __shfl_xor(rsum, 32, 64);
      lrun += rsum;

      // ---- P -> bf16 B-fragments in-register ----
      u32 wv[8];
      #pragma unroll
      for (int j = 0; j < 8; ++j){
        float lo = sacc[2 * j], hp = sacc[2 * j + 1];
        asm("v_cvt_pk_bf16_f32 %0, %1, %2" : "=v"(wv[j]) : "v"(lo), "v"(hp));
      }
      asm volatile("v_permlane32_swap_b32 %0, %1" : "+v"(wv[0]), "+v"(wv[2]));
      asm volatile("v_permlane32_swap_b32 %0, %1" : "+v"(wv[1]), "+v"(wv[3]));
      asm volatile("v_permlane32_swap_b32 %0, %1" : "+v"(wv[4]), "+v"(wv[6]));
      asm volatile("v_permlane32_swap_b32 %0, %1" : "+v"(wv[5]), "+v"(wv[7]));
      u32x4 pa0 = (u32x4){wv[0], wv[1], wv[2], wv[3]};
      u32x4 pa1 = (u32x4){wv[4], wv[5], wv[6], wv[7]};

      // ---- PV swapped: acco[db] += mfma(V^T, P^T) ----
      __builtin_amdgcn_s_setprio(1);
      #pragma unroll
      for (int ks = 0; ks < 2; ++ks){
        #pragma unroll
        for (int db = 0; db < 2; ++db){
          bf16x8 av = *reinterpret_cast<const bf16x8*>(
              &Vld[cur][(db * 32 + l32) * 32 + (((ks * 2 + hi) ^ (l32 & 3)) * 8)]);
          acco[db] = __builtin_amdgcn_mfma_f32_32x32x16_bf16(
              av, __builtin_bit_cast(bf16x8, ks ? pa1 : pa0), acco[db], 0, 0, 0);
        }
      }
      __builtin_amdgcn_s_setprio(0);
    }

    asm volatile("s_waitcnt vmcnt(0)" ::: "memory");
    __syncthreads();
    cur ^= 1;
  }

  if (seg < 0){
    // ---- direct epilogue ----
    const float linv = 1.0f / lrun;
    const int srow = q0 + l32;
    bf16_t* orow = attn_out + ((size_t)b * Slen + srow) * (NH * HD) + h * HD;
    #pragma unroll
    for (int db = 0; db < 2; ++db){
      #pragma unroll
      for (int j = 0; j < 8; ++j){
        int r = 2 * j;
        int d = db * 32 + (r & 3) + 8 * (r >> 2) + 4 * hi;
        u32 pw;
        float lo = acco[db][r] * linv, hp = acco[db][r + 1] * linv;
        asm("v_cvt_pk_bf16_f32 %0, %1, %2" : "=v"(pw) : "v"(lo), "v"(hp));
        *reinterpret_cast<u32*>(orow + d) = pw;
      }
    }
  } else {
    // ---- partial epilogue: packed bf16 O^T pairs [d/2][q], fp32 m/l ----
    const int slot = (bh * 16 + (qt - 16)) * 2 + seg;
    u32* po = part_O + ((size_t)slot * 2 + w) * 1024;
    float* pml = part_ml + ((size_t)slot * 2 + w) * 64;
    #pragma unroll
    for (int db = 0; db < 2; ++db){
      #pragma unroll
      for (int j = 0; j < 8; ++j){
        int r = 2 * j;
        int d = db * 32 + (r & 3) + 8 * (r >> 2) + 4 * hi;   // even
        u32 pw;
        float lo = acco[db][r], hp = acco[db][r + 1];
        asm("v_cvt_pk_bf16_f32 %0, %1, %2" : "=v"(pw) : "v"(lo), "v"(hp));
        po[(d >> 1) * 32 + l32] = pw;
      }
    }
    if (hi == 0){ pml[l32] = mrun; pml[32 + l32] = lrun; }
  }
}

// ---------------- Combine: merge 2 segments per q-row (qt >= 16) ----------------
__launch_bounds__(128)
__global__ void combine_kernel(const u32* __restrict__ part_O,
                               const float* __restrict__ part_ml,
                               bf16_t* __restrict__ attn_out)
{
  const int idx = blockIdx.x;           // 0..575
  const int bh = idx % 36, qtm = idx / 36;
  const int qt = 16 + qtm;
  const int b = bh / NH, h = bh % NH;
  const int t = threadIdx.x;
  const int q = t & 31, wg = (t >> 5) & 1, half = t >> 6;
  const int slot0 = (bh * 16 + qtm) * 2;

  const float* pml0 = part_ml + ((size_t)(slot0 + 0) * 2 + wg) * 64;
  const float* pml1 = part_ml + ((size_t)(slot0 + 1) * 2 + wg) * 64;
  float m1 = pml0[q], l1 = pml0[32 + q];
  float m2 = pml1[q], l2 = pml1[32 + q];
  float m = fmaxf(m1, m2);
  float a1 = __builtin_amdgcn_exp2f(m1 - m);
  float a2 = __builtin_amdgcn_exp2f(m2 - m);
  float linv = 1.0f / (l1 * a1 + l2 * a2);
  a1 *= linv; a2 *= linv;

  const u32* po0 = part_O + ((size_t)(slot0 + 0) * 2 + wg) * 1024;
  const u32* po1 = part_O + ((size_t)(slot0 + 1) * 2 + wg) * 1024;
  const int s = qt * 64 + wg * 32 + q;
  bf16_t* orow = attn_out + ((size_t)b * Slen + s) * (NH * HD) + h * HD;

  #pragma unroll
  for (int u = 0; u < 16; ++u){
    int dp = half * 16 + u;
    u32 v1 = po0[dp * 32 + q], v2 = po1[dp * 32 + q];
    float lo = a1 * __builtin_bit_cast(float, v1 << 16)
             + a2 * __builtin_bit_cast(float, v2 << 16);
    float hv = a1 * __builtin_bit_cast(float, v1 & 0xffff0000u)
             + a2 * __builtin_bit_cast(float, v2 & 0xffff0000u);
    u32 pw;
    asm("v_cvt_pk_bf16_f32 %0, %1, %2" : "=v"(pw) : "v"(lo), "v"(hv));
    *reinterpret_cast<u32*>(orow + 2 * dp) = pw;
  }
}

// ---------------- Output GEMM v2: ab (8192x576 bf16) @ Wob^T -> fp32, gload_lds dbuf ----------------
__launch_bounds__(256)
__global__ void out_gemm_kernel(const bf16_t* __restrict__ A,
                                const bf16_t* __restrict__ Wob,
                                float* __restrict__ out)
{
  __shared__ bf16_t Ald[2][128 * 64];
  __shared__ bf16_t Bld[2][64 * 64];
  const int t = threadIdx.x, l = t & 63, w = t >> 6;
  const int wm = w >> 1, wn = w & 1;
  const int lane16 = l & 15, grp = l >> 4;
  const int m0 = blockIdx.x * 128;
  const int nt = blockIdx.y;
  const int nrow0 = nt * 64;

  const int sr = l >> 3;
  const int sc = ((l & 7) ^ sr) * 8;

  f32x4 acc[4][2];
  #pragma unroll
  for (int mi = 0; mi < 4; ++mi)
    #pragma unroll
    for (int ni = 0; ni < 2; ++ni)
      acc[mi][ni] = (f32x4){0.f, 0.f, 0.f, 0.f};

  auto STAGE = [&](int kt, int buf){
    const int k0 = kt * 64;
    #pragma unroll
    for (int u = 0; u < 4; ++u)
      gload16(A + (size_t)(m0 + w * 32 + u * 8 + sr) * Hdim + k0 + sc,
              &Ald[buf][(w * 32 + u * 8) * 64]);
    #pragma unroll
    for (int u = 0; u < 2; ++u)
      gload16(Wob + (size_t)(nrow0 + w * 16 + u * 8 + sr) * Hdim + k0 + sc,
              &Bld[buf][(w * 16 + u * 8) * 64]);
  };

  STAGE(0, 0);
  asm volatile("s_waitcnt vmcnt(0)" ::: "memory");
  __syncthreads();

  const int sl7 = lane16 & 7;
  for (int kt = 0; kt < 9; ++kt){
    const int buf = kt & 1;
    if (kt + 1 < 9) STAGE(kt + 1, buf ^ 1);
    #pragma unroll
    for (int ks = 0; ks < 2; ++ks){
      bf16x8 a[4], bb[2];
      #pragma unroll
      for (int mi = 0; mi < 4; ++mi){
        int row = wm * 64 + mi * 16 + lane16;
        a[mi] = *reinterpret_cast<const bf16x8*>(&Ald[buf][row * 64 + (((ks * 4 + grp) ^ sl7) * 8)]);
      }
      #pragma unroll
      for (int ni = 0; ni < 2; ++ni){
        int row = wn * 32 + ni * 16 + lane16;
        bb[ni] = *reinterpret_cast<const bf16x8*>(&Bld[buf][row * 64 + (((ks * 4 + grp) ^ sl7) * 8)]);
      }
      #pragma unroll
      for (int mi = 0; mi < 4; ++mi)
        #pragma unroll
        for (int ni = 0; ni < 2; ++ni)
          acc[mi][ni] = __builtin_amdgcn_mfma_f32_16x16x32_bf16(a[mi], bb[ni], acc[mi][ni], 0, 0, 0);
    }
    if (kt + 1 < 9){
      asm volatile("s_waitcnt vmcnt(0)" ::: "memory");
      __syncthreads();
    }
  }

  #pragma unroll
  for (int mi = 0; mi < 4; ++mi){
    #pragma unroll
    for (int ni = 0; ni < 2; ++ni){
      #pragma unroll
      for (int j = 0; j < 4; ++j){
        int m = m0 + wm * 64 + mi * 16 + grp * 4 + j;
        int n = nrow0 + wn * 32 + ni * 16 + lane16;
        out[(size_t)m * Hdim + n] = acc[mi][ni][j];
      }
    }
  }
}

extern "C" void kernel_launch(void* const* d_in, const int* in_sizes, int n_in,
                              void* d_out, int out_size, void* d_ws, size_t ws_size,
                              hipStream_t stream) {
  const float* X   = (const float*)d_in[0];
  const int* pos   = (const int*)d_in[2];
  const float* Wq  = (const float*)d_in[3];
  const float* Wk  = (const float*)d_in[4];
  const float* Wv  = (const float*)d_in[5];
  const float* Wo  = (const float*)d_in[6];
  float* out = (float*)d_out;

  char* ws = (char*)d_ws;
  float* cost = (float*)ws;                                      // 256 KB
  float* sint = (float*)(ws + 262144);                           // 256 KB
  bf16_t* qb  = (bf16_t*)(ws + 524288);                          // 9.44 MB
  bf16_t* kb  = qb + (size_t)Bsz * NH * Slen * HD;               // 3.15 MB
  bf16_t* vt  = kb + (size_t)Bsz * NKV * Slen * HD;              // 3.15 MB
  bf16_t* Xb  = vt + (size_t)Bsz * NKV * Slen * HD;              // 9.44 MB
  bf16_t* ab  = Xb;                                              // alias: Xb dead after qkv_gemm
  bf16_t* Wb  = Xb + (size_t)8192 * 576;                         // 1.11 MB
  bf16_t* Wob = Wb + (size_t)960 * 576;                          // 0.66 MB
  u32*  part_O  = (u32*)(Wob + (size_t)576 * 576);               // 9.44 MB
  float* part_ml = (float*)(part_O + (size_t)1152 * 2 * 1024);   // 0.59 MB

  const float QSCALE = 0.125f * 1.44269504088896f;

  rope_table_kernel<<<dim3((Slen * 32 + 255) / 256), dim3(256), 0, stream>>>(cost, sint);
  precast_kernel<<<dim3(2736), dim3(256), 0, stream>>>(X, Wq, Wk, Wv, Wo, Xb, Wb, Wob);
  qkv_gemm_kernel<<<dim3(64, 15), dim3(256), 0, stream>>>(Xb, Wb, qb, kb, vt);
  rope_apply_all<<<dim3((Bsz * (NH + NKV) * Slen + 255) / 256), dim3(256), 0, stream>>>(qb, pos, cost, sint, QSCALE);
  flash_attn_kernel<<<dim3(1728), dim3(128), 0, stream>>>(qb, kb, vt, ab, part_O, part_ml);
  combine_kernel<<<dim3(576), dim3(128), 0, stream>>>(part_O, part_ml, ab);
  out_gemm_kernel<<<dim3(64, 9), dim3(256), 0, stream>>>(ab, Wob, out);
}

// Round 10
// 113.459 us; speedup vs baseline: 1.6118x; 1.0482x over previous
//
#include <hip/hip_runtime.h>
#include <hip/hip_bf16.h>
#include <math.h>

#define Bsz 4
#define Slen 2048
#define Hdim 576
#define NH 9
#define NKV 3
#define HD 64

typedef __bf16 bf16_t;
typedef __bf16 bf16x8 __attribute__((ext_vector_type(8)));
typedef float f32x4 __attribute__((ext_vector_type(4)));
typedef float f32x16 __attribute__((ext_vector_type(16)));
typedef unsigned int u32;
typedef unsigned int u32x4 __attribute__((ext_vector_type(4)));

static __device__ __forceinline__ bf16x8 load_cvt8(const float* __restrict__ src){
  float4 f0 = *reinterpret_cast<const float4*>(src);
  float4 f1 = *reinterpret_cast<const float4*>(src + 4);
  bf16x8 v;
  v[0]=(bf16_t)f0.x; v[1]=(bf16_t)f0.y; v[2]=(bf16_t)f0.z; v[3]=(bf16_t)f0.w;
  v[4]=(bf16_t)f1.x; v[5]=(bf16_t)f1.y; v[6]=(bf16_t)f1.z; v[7]=(bf16_t)f1.w;
  return v;
}

// async global->LDS, 16B per lane
static __device__ __forceinline__ void gload16(const bf16_t* g, bf16_t* l){
  __builtin_amdgcn_global_load_lds((const __attribute__((address_space(1))) void*)g,
                                   (__attribute__((address_space(3))) void*)l, 16, 0, 0);
}

// ---------------- Setup: RoPE tables + precast X/W to bf16 (fused, one launch) ----------------
__global__ void setup_kernel(const float* __restrict__ X,
                             const float* __restrict__ Wq,
                             const float* __restrict__ Wk,
                             const float* __restrict__ Wv,
                             const float* __restrict__ Wo,
                             bf16_t* __restrict__ Xb,
                             bf16_t* __restrict__ Wb,
                             bf16_t* __restrict__ Wob,
                             float* __restrict__ cost,
                             float* __restrict__ sint)
{
  const int bid = blockIdx.x;
  if (bid < 256){                       // RoPE tables: Slen*32 = 65536 entries
    int i = bid * 256 + threadIdx.x;
    int j = i & 31;
    int p = i >> 5;
    double invf = pow(100000.0, -(double)j / 32.0);
    double ang = (double)p * invf;
    cost[i] = (float)cos(ang);
    sint[i] = (float)sin(ang);
    return;
  }
  const int NX  = 8192 * 576 / 8;
  const int NWq = 576 * 576 / 8;
  const int NWk = 192 * 576 / 8;
  int i = (bid - 256) * 256 + threadIdx.x;
  const int total = NX + NWq + 2 * NWk + NWq;
  if (i >= total) return;
  const float* src; bf16_t* dst; int off;
  if (i < NX)                    { src = X;  dst = Xb;            off = i; }
  else if (i < NX + NWq)         { src = Wq; dst = Wb;            off = i - NX; }
  else if (i < NX + NWq + NWk)   { src = Wk; dst = Wb + 331776;   off = i - NX - NWq; }
  else if (i < NX + NWq + 2*NWk) { src = Wv; dst = Wb + 442368;   off = i - NX - NWq - NWk; }
  else                           { src = Wo; dst = Wob;           off = i - NX - NWq - 2*NWk; }
  *reinterpret_cast<bf16x8*>(dst + (size_t)off * 8) = load_cvt8(src + (size_t)off * 8);
}

// ---------------- QKV projection GEMM (M=8192, K=576, N=960), bf16 gload_lds dbuf ----------------
__launch_bounds__(256)
__global__ void qkv_gemm_kernel(const bf16_t* __restrict__ Xb,
                                const bf16_t* __restrict__ Wb,
                                bf16_t* __restrict__ qbuf,
                                bf16_t* __restrict__ kbuf,
                                bf16_t* __restrict__ vtbuf)
{
  __shared__ bf16_t Ald[2][128 * 64];
  __shared__ bf16_t Bld[2][64 * 64];
  const int t = threadIdx.x, l = t & 63, w = t >> 6;
  const int wm = w >> 1, wn = w & 1;
  const int lane16 = l & 15, grp = l >> 4;
  const int m0 = blockIdx.x * 128;
  const int nt = blockIdx.y;
  const int nrow0 = nt * 64;

  const int sr = l >> 3;
  const int sc = ((l & 7) ^ sr) * 8;

  f32x4 acc[4][2];
  #pragma unroll
  for (int mi = 0; mi < 4; ++mi)
    #pragma unroll
    for (int ni = 0; ni < 2; ++ni)
      acc[mi][ni] = (f32x4){0.f, 0.f, 0.f, 0.f};

  auto STAGE = [&](int kt, int buf){
    const int k0 = kt * 64;
    #pragma unroll
    for (int u = 0; u < 4; ++u)
      gload16(Xb + (size_t)(m0 + w * 32 + u * 8 + sr) * Hdim + k0 + sc,
              &Ald[buf][(w * 32 + u * 8) * 64]);
    #pragma unroll
    for (int u = 0; u < 2; ++u)
      gload16(Wb + (size_t)(nrow0 + w * 16 + u * 8 + sr) * Hdim + k0 + sc,
              &Bld[buf][(w * 16 + u * 8) * 64]);
  };

  STAGE(0, 0);
  asm volatile("s_waitcnt vmcnt(0)" ::: "memory");
  __syncthreads();

  const int sl7 = lane16 & 7;
  for (int kt = 0; kt < 9; ++kt){
    const int buf = kt & 1;
    if (kt + 1 < 9) STAGE(kt + 1, buf ^ 1);
    #pragma unroll
    for (int ks = 0; ks < 2; ++ks){
      bf16x8 a[4], bb[2];
      #pragma unroll
      for (int mi = 0; mi < 4; ++mi){
        int row = wm * 64 + mi * 16 + lane16;
        a[mi] = *reinterpret_cast<const bf16x8*>(&Ald[buf][row * 64 + (((ks * 4 + grp) ^ sl7) * 8)]);
      }
      #pragma unroll
      for (int ni = 0; ni < 2; ++ni){
        int row = wn * 32 + ni * 16 + lane16;
        bb[ni] = *reinterpret_cast<const bf16x8*>(&Bld[buf][row * 64 + (((ks * 4 + grp) ^ sl7) * 8)]);
      }
      #pragma unroll
      for (int mi = 0; mi < 4; ++mi)
        #pragma unroll
        for (int ni = 0; ni < 2; ++ni)
          acc[mi][ni] = __builtin_amdgcn_mfma_f32_16x16x32_bf16(a[mi], bb[ni], acc[mi][ni], 0, 0, 0);
    }
    if (kt + 1 < 9){
      asm volatile("s_waitcnt vmcnt(0)" ::: "memory");
      __syncthreads();
    }
  }

  #pragma unroll
  for (int mi = 0; mi < 4; ++mi){
    #pragma unroll
    for (int ni = 0; ni < 2; ++ni){
      #pragma unroll
      for (int j = 0; j < 4; ++j){
        int m = m0 + wm * 64 + mi * 16 + grp * 4 + j;
        int dl = wn * 32 + ni * 16 + lane16;
        int b = m >> 11;
        int s = m & 2047;
        bf16_t v = (bf16_t)acc[mi][ni][j];
        if (nt < 9)
          qbuf[(((size_t)b * NH + nt) * Slen + s) * HD + dl] = v;
        else if (nt < 12)
          kbuf[(((size_t)b * NKV + (nt - 9)) * Slen + s) * HD + dl] = v;
        else
          vtbuf[(((size_t)b * NKV + (nt - 12)) * HD + dl) * Slen + s] = v;
      }
    }
  }
}

// ---------------- RoPE in-place on q+k (contiguous) ----------------
__global__ void rope_apply_all(bf16_t* __restrict__ qkbuf, const int* __restrict__ pos_ids,
                               const float* __restrict__ cost, const float* __restrict__ sint,
                               float qscale)
{
  int idx = blockIdx.x * blockDim.x + threadIdx.x;
  const int qrows = Bsz * NH * Slen;
  const int total = qrows + Bsz * NKV * Slen;
  if (idx >= total) return;
  const bool isq = idx < qrows;
  int s = idx & (Slen - 1);
  int b = isq ? idx / (NH * Slen) : (idx - qrows) / (NKV * Slen);
  float scale = isq ? qscale : 1.0f;
  bf16_t* row = qkbuf + (size_t)idx * HD;
  int pos = pos_ids[b * Slen + s];
  const float* cp = cost + (size_t)pos * 32;
  const float* sp = sint + (size_t)pos * 32;
  float x[64];
  #pragma unroll
  for (int v = 0; v < 8; ++v){
    bf16x8 t8 = *reinterpret_cast<const bf16x8*>(row + v * 8);
    #pragma unroll
    for (int i = 0; i < 8; ++i) x[v * 8 + i] = (float)t8[i];
  }
  bf16_t o[64];
  #pragma unroll
  for (int j = 0; j < 32; ++j){
    float c = cp[j], sn = sp[j];
    o[j]      = (bf16_t)((x[j] * c - x[j + 32] * sn) * scale);
    o[j + 32] = (bf16_t)((x[j + 32] * c + x[j] * sn) * scale);
  }
  #pragma unroll
  for (int v = 0; v < 8; ++v)
    *reinterpret_cast<bf16x8*>(row + v * 8) = *reinterpret_cast<bf16x8*>(o + v * 8);
}

// ---------------- Flash attention v8: split-K + KVBLK=32 + 3-deep counted-vmcnt pipeline ----------------
// Block = 64 q-rows (2 waves x 32). KV tiles of 32. qt<16 direct; qt>=16 split at tile 32 ->
// partials merged by combine_kernel. Per-iter: {vmcnt(8|0) -> barrier -> STAGE(kt+2) -> compute}.
// V LDS swizzle: chunk stored at c ^ ((d>>1)&3) -> 2-way banks on PV reads (was 8-way).
__launch_bounds__(128)
__global__ void flash_attn_kernel(const bf16_t* __restrict__ qbuf,
                                  const bf16_t* __restrict__ kbuf,
                                  const bf16_t* __restrict__ vtbuf,
                                  bf16_t* __restrict__ attn_out,
                                  u32* __restrict__ part_O,
                                  float* __restrict__ part_ml)
{
  __shared__ bf16_t Kld[3][32 * 64];   // 4KB per buf
  __shared__ bf16_t Vld[3][64 * 32];   // 4KB per buf
  const int t = threadIdx.x, l = t & 63, w = t >> 6;
  const int l32 = l & 31, hi = l >> 5;

  // heavy-first: v<16 -> seg0 of qt=16+v (32 tiles); then (direct qt 15..0) x (seg1 qt 31..16)
  const int flat = blockIdx.x;
  const int v = flat / 36;
  const int bh = flat % 36;
  int qt, t0, t1, seg;
  if (v < 16){ qt = 16 + v; t0 = 0; t1 = 32; seg = 0; }
  else {
    int i = (v - 16) >> 1;
    if (((v - 16) & 1) == 0){ qt = 15 - i; t0 = 0; t1 = 2 * qt + 2; seg = -1; }
    else                    { qt = 31 - i; t0 = 32; t1 = 2 * qt + 2; seg = 1; }
  }
  const int b = bh / NH, h = bh % NH, kvh = h / (NH / NKV);

  const bf16_t* qp = qbuf + ((size_t)b * NH + h) * Slen * HD;
  const bf16_t* kp = kbuf + ((size_t)b * NKV + kvh) * Slen * HD;
  const bf16_t* vp = vtbuf + ((size_t)b * NKV + kvh) * HD * Slen;

  // staging lane geometry (pre-swizzled global source, linear LDS dest)
  const int krow = l >> 3;                            // 0..7
  const int ksc  = ((l & 7) ^ krow) * 8;              // Kld[r][c]=K[r][c^(r&7)]
  const int vrow = l >> 2;                            // 0..15
  const int vsc  = ((l & 3) ^ ((vrow >> 1) & 3)) * 8; // Vld[d][c]=V[d][c^((d>>1)&3)]

  auto STAGE = [&](int kt, int buf){
    const int k0 = kt * 32;
    #pragma unroll
    for (int u = 0; u < 2; ++u){
      int ub = w * 2 + u;                        // 0..3
      gload16(kp + (size_t)(k0 + ub * 8 + krow) * HD + ksc, &Kld[buf][ub * 512]);
      gload16(vp + (size_t)(ub * 16 + vrow) * Slen + k0 + vsc, &Vld[buf][ub * 512]);
    }
  };

  STAGE(t0, 0);
  if (t0 + 1 < t1) STAGE(t0 + 1, 1);

  const int q0 = qt * 64 + w * 32;
  bf16x8 aq[4];
  #pragma unroll
  for (int ds = 0; ds < 4; ++ds)
    aq[ds] = *reinterpret_cast<const bf16x8*>(qp + (size_t)(q0 + l32) * HD + ds * 16 + hi * 8);

  f32x16 acco[2];   // O^T[d = db*32 + crow(r,hi)][q = l32], unnormalized
  #pragma unroll
  for (int db = 0; db < 2; ++db)
    #pragma unroll
    for (int r = 0; r < 16; ++r) acco[db][r] = 0.f;
  float mrun = -1e30f, lrun = 0.f;

  int cur = 0;
  const int dt = 2 * qt + w;                    // this wave's diagonal tile
  for (int kb = t0; kb < t1; ++kb){
    // stage(kb) ready: 8 newer ops (stage kb+1) may remain in flight
    if (kb + 1 < t1) asm volatile("s_waitcnt vmcnt(8)" ::: "memory");
    else             asm volatile("s_waitcnt vmcnt(0)" ::: "memory");
    __syncthreads();

    if (kb + 2 < t1){
      int sb = cur + 2; if (sb >= 3) sb -= 3;
      STAGE(kb + 2, sb);                        // lands during compute(kb) + compute(kb+1)
    }

    if (kb <= dt){                              // wave-uniform; kb > dt fully masked (wave0 tail)
      // ---- QK^T swapped: sacc[r] = S^T[k = crow(r,hi)][q = l32] ----
      f32x16 sacc;
      #pragma unroll
      for (int r = 0; r < 16; ++r) sacc[r] = 0.f;
      __builtin_amdgcn_s_setprio(1);
      #pragma unroll
      for (int ds = 0; ds < 4; ++ds){
        bf16x8 ak = *reinterpret_cast<const bf16x8*>(
            &Kld[cur][l32 * 64 + (((ds * 2 + hi) ^ (l32 & 7)) * 8)]);
        sacc = __builtin_amdgcn_mfma_f32_32x32x16_bf16(ak, aq[ds], sacc, 0, 0, 0);
      }
      __builtin_amdgcn_s_setprio(0);

      // ---- causal mask (diagonal tile only) ----
      if (kb == dt){
        #pragma unroll
        for (int r = 0; r < 16; ++r){
          int crow = (r & 3) + 8 * (r >> 2) + 4 * hi;
          if (crow > l32) sacc[r] = -1e30f;
        }
      }

      // ---- row max: in-lane tree + 1 cross-lane (l <-> l^32) ----
      float tmax = fmaxf(sacc[0], sacc[1]);
      #pragma unroll
      for (int r = 2; r < 16; ++r) tmax = fmaxf(tmax, sacc[r]);
      tmax = fmaxf(tmax, __shfl_xor(tmax, 32, 64));

      // ---- defer-max (THR=8, log2 domain) ----
      if (__ballot(tmax - mrun > 8.f)){
        float mnew = fmaxf(mrun, tmax);
        float sf = __builtin_amdgcn_exp2f(mrun - mnew);
        lrun *= sf;
        #pragma unroll
        for (int db = 0; db < 2; ++db)
          #pragma unroll
          for (int r = 0; r < 16; ++r) acco[db][r] *= sf;
        mrun = mnew;
      }

      // ---- exp2 + row sum ----
      float rsum = 0.f;
      #pragma unroll
      for (int r = 0; r < 16; ++r){
        float pv = __builtin_amdgcn_exp2f(sacc[r] - mrun);
        sacc[r] = pv;
        rsum += pv;
      }
      rsum += __shfl_xor(rsum, 32, 64);
      lrun += rsum;

      // ---- P -> bf16 B-fragments in-register ----
      u32 wv[8];
      #pragma unroll
      for (int j = 0; j < 8; ++j){
        float lo = sacc[2 * j], hp = sacc[2 * j + 1];
        asm("v_cvt_pk_bf16_f32 %0, %1, %2" : "=v"(wv[j]) : "v"(lo), "v"(hp));
      }
      asm volatile("v_permlane32_swap_b32 %0, %1" : "+v"(wv[0]), "+v"(wv[2]));
      asm volatile("v_permlane32_swap_b32 %0, %1" : "+v"(wv[1]), "+v"(wv[3]));
      asm volatile("v_permlane32_swap_b32 %0, %1" : "+v"(wv[4]), "+v"(wv[6]));
      asm volatile("v_permlane32_swap_b32 %0, %1" : "+v"(wv[5]), "+v"(wv[7]));
      u32x4 pa0 = (u32x4){wv[0], wv[1], wv[2], wv[3]};
      u32x4 pa1 = (u32x4){wv[4], wv[5], wv[6], wv[7]};

      // ---- PV swapped: acco[db] += mfma(V^T, P^T) ----
      __builtin_amdgcn_s_setprio(1);
      #pragma unroll
      for (int ks = 0; ks < 2; ++ks){
        #pragma unroll
        for (int db = 0; db < 2; ++db){
          bf16x8 av = *reinterpret_cast<const bf16x8*>(
              &Vld[cur][(db * 32 + l32) * 32 + (((ks * 2 + hi) ^ ((l32 >> 1) & 3)) * 8)]);
          acco[db] = __builtin_amdgcn_mfma_f32_32x32x16_bf16(
              av, __builtin_bit_cast(bf16x8, ks ? pa1 : pa0), acco[db], 0, 0, 0);
        }
      }
      __builtin_amdgcn_s_setprio(0);
    }

    cur = (cur + 1 == 3) ? 0 : cur + 1;
  }

  if (seg < 0){
    // ---- direct epilogue ----
    const float linv = 1.0f / lrun;
    const int srow = q0 + l32;
    bf16_t* orow = attn_out + ((size_t)b * Slen + srow) * (NH * HD) + h * HD;
    #pragma unroll
    for (int db = 0; db < 2; ++db){
      #pragma unroll
      for (int j = 0; j < 8; ++j){
        int r = 2 * j;
        int d = db * 32 + (r & 3) + 8 * (r >> 2) + 4 * hi;
        u32 pw;
        float lo = acco[db][r] * linv, hp = acco[db][r + 1] * linv;
        asm("v_cvt_pk_bf16_f32 %0, %1, %2" : "=v"(pw) : "v"(lo), "v"(hp));
        *reinterpret_cast<u32*>(orow + d) = pw;
      }
    }
  } else {
    // ---- partial epilogue: packed bf16 O^T pairs [d/2][q], fp32 m/l ----
    const int slot = (bh * 16 + (qt - 16)) * 2 + seg;
    u32* po = part_O + ((size_t)slot * 2 + w) * 1024;
    float* pml = part_ml + ((size_t)slot * 2 + w) * 64;
    #pragma unroll
    for (int db = 0; db < 2; ++db){
      #pragma unroll
      for (int j = 0; j < 8; ++j){
        int r = 2 * j;
        int d = db * 32 + (r & 3) + 8 * (r >> 2) + 4 * hi;   // even
        u32 pw;
        float lo = acco[db][r], hp = acco[db][r + 1];
        asm("v_cvt_pk_bf16_f32 %0, %1, %2" : "=v"(pw) : "v"(lo), "v"(hp));
        po[(d >> 1) * 32 + l32] = pw;
      }
    }
    if (hi == 0){ pml[l32] = mrun; pml[32 + l32] = lrun; }
  }
}

// ---------------- Combine: merge 2 segments per q-row (qt >= 16) ----------------
__launch_bounds__(128)
__global__ void combine_kernel(const u32* __restrict__ part_O,
                               const float* __restrict__ part_ml,
                               bf16_t* __restrict__ attn_out)
{
  const int idx = blockIdx.x;           // 0..575
  const int bh = idx % 36, qtm = idx / 36;
  const int qt = 16 + qtm;
  const int b = bh / NH, h = bh % NH;
  const int t = threadIdx.x;
  const int q = t & 31, wg = (t >> 5) & 1, half = t >> 6;
  const int slot0 = (bh * 16 + qtm) * 2;

  const float* pml0 = part_ml + ((size_t)(slot0 + 0) * 2 + wg) * 64;
  const float* pml1 = part_ml + ((size_t)(slot0 + 1) * 2 + wg) * 64;
  float m1 = pml0[q], l1 = pml0[32 + q];
  float m2 = pml1[q], l2 = pml1[32 + q];
  float m = fmaxf(m1, m2);
  float a1 = __builtin_amdgcn_exp2f(m1 - m);
  float a2 = __builtin_amdgcn_exp2f(m2 - m);
  float linv = 1.0f / (l1 * a1 + l2 * a2);
  a1 *= linv; a2 *= linv;

  const u32* po0 = part_O + ((size_t)(slot0 + 0) * 2 + wg) * 1024;
  const u32* po1 = part_O + ((size_t)(slot0 + 1) * 2 + wg) * 1024;
  const int s = qt * 64 + wg * 32 + q;
  bf16_t* orow = attn_out + ((size_t)b * Slen + s) * (NH * HD) + h * HD;

  #pragma unroll
  for (int u = 0; u < 16; ++u){
    int dp = half * 16 + u;
    u32 v1 = po0[dp * 32 + q], v2 = po1[dp * 32 + q];
    float lo = a1 * __builtin_bit_cast(float, v1 << 16)
             + a2 * __builtin_bit_cast(float, v2 << 16);
    float hv = a1 * __builtin_bit_cast(float, v1 & 0xffff0000u)
             + a2 * __builtin_bit_cast(float, v2 & 0xffff0000u);
    u32 pw;
    asm("v_cvt_pk_bf16_f32 %0, %1, %2" : "=v"(pw) : "v"(lo), "v"(hv));
    *reinterpret_cast<u32*>(orow + 2 * dp) = pw;
  }
}

// ---------------- Output GEMM: ab (8192x576 bf16) @ Wob^T -> fp32, gload_lds dbuf ----------------
__launch_bounds__(256)
__global__ void out_gemm_kernel(const bf16_t* __restrict__ A,
                                const bf16_t* __restrict__ Wob,
                                float* __restrict__ out)
{
  __shared__ bf16_t Ald[2][128 * 64];
  __shared__ bf16_t Bld[2][64 * 64];
  const int t = threadIdx.x, l = t & 63, w = t >> 6;
  const int wm = w >> 1, wn = w & 1;
  const int lane16 = l & 15, grp = l >> 4;
  const int m0 = blockIdx.x * 128;
  const int nt = blockIdx.y;
  const int nrow0 = nt * 64;

  const int sr = l >> 3;
  const int sc = ((l & 7) ^ sr) * 8;

  f32x4 acc[4][2];
  #pragma unroll
  for (int mi = 0; mi < 4; ++mi)
    #pragma unroll
    for (int ni = 0; ni < 2; ++ni)
      acc[mi][ni] = (f32x4){0.f, 0.f, 0.f, 0.f};

  auto STAGE = [&](int kt, int buf){
    const int k0 = kt * 64;
    #pragma unroll
    for (int u = 0; u < 4; ++u)
      gload16(A + (size_t)(m0 + w * 32 + u * 8 + sr) * Hdim + k0 + sc,
              &Ald[buf][(w * 32 + u * 8) * 64]);
    #pragma unroll
    for (int u = 0; u < 2; ++u)
      gload16(Wob + (size_t)(nrow0 + w * 16 + u * 8 + sr) * Hdim + k0 + sc,
              &Bld[buf][(w * 16 + u * 8) * 64]);
  };

  STAGE(0, 0);
  asm volatile("s_waitcnt vmcnt(0)" ::: "memory");
  __syncthreads();

  const int sl7 = lane16 & 7;
  for (int kt = 0; kt < 9; ++kt){
    const int buf = kt & 1;
    if (kt + 1 < 9) STAGE(kt + 1, buf ^ 1);
    #pragma unroll
    for (int ks = 0; ks < 2; ++ks){
      bf16x8 a[4], bb[2];
      #pragma unroll
      for (int mi = 0; mi < 4; ++mi){
        int row = wm * 64 + mi * 16 + lane16;
        a[mi] = *reinterpret_cast<const bf16x8*>(&Ald[buf][row * 64 + (((ks * 4 + grp) ^ sl7) * 8)]);
      }
      #pragma unroll
      for (int ni = 0; ni < 2; ++ni){
        int row = wn * 32 + ni * 16 + lane16;
        bb[ni] = *reinterpret_cast<const bf16x8*>(&Bld[buf][row * 64 + (((ks * 4 + grp) ^ sl7) * 8)]);
      }
      #pragma unroll
      for (int mi = 0; mi < 4; ++mi)
        #pragma unroll
        for (int ni = 0; ni < 2; ++ni)
          acc[mi][ni] = __builtin_amdgcn_mfma_f32_16x16x32_bf16(a[mi], bb[ni], acc[mi][ni], 0, 0, 0);
    }
    if (kt + 1 < 9){
      asm volatile("s_waitcnt vmcnt(0)" ::: "memory");
      __syncthreads();
    }
  }

  #pragma unroll
  for (int mi = 0; mi < 4; ++mi){
    #pragma unroll
    for (int ni = 0; ni < 2; ++ni){
      #pragma unroll
      for (int j = 0; j < 4; ++j){
        int m = m0 + wm * 64 + mi * 16 + grp * 4 + j;
        int n = nrow0 + wn * 32 + ni * 16 + lane16;
        out[(size_t)m * Hdim + n] = acc[mi][ni][j];
      }
    }
  }
}

extern "C" void kernel_launch(void* const* d_in, const int* in_sizes, int n_in,
                              void* d_out, int out_size, void* d_ws, size_t ws_size,
                              hipStream_t stream) {
  const float* X   = (const float*)d_in[0];
  const int* pos   = (const int*)d_in[2];
  const float* Wq  = (const float*)d_in[3];
  const float* Wk  = (const float*)d_in[4];
  const float* Wv  = (const float*)d_in[5];
  const float* Wo  = (const float*)d_in[6];
  float* out = (float*)d_out;

  char* ws = (char*)d_ws;
  float* cost = (float*)ws;                                      // 256 KB
  float* sint = (float*)(ws + 262144);                           // 256 KB
  bf16_t* qb  = (bf16_t*)(ws + 524288);                          // 9.44 MB
  bf16_t* kb  = qb + (size_t)Bsz * NH * Slen * HD;               // 3.15 MB
  bf16_t* vt  = kb + (size_t)Bsz * NKV * Slen * HD;              // 3.15 MB
  bf16_t* Xb  = vt + (size_t)Bsz * NKV * Slen * HD;              // 9.44 MB
  bf16_t* ab  = Xb;                                              // alias: Xb dead after qkv_gemm
  bf16_t* Wb  = Xb + (size_t)8192 * 576;                         // 1.11 MB
  bf16_t* Wob = Wb + (size_t)960 * 576;                          // 0.66 MB
  u32*  part_O  = (u32*)(Wob + (size_t)576 * 576);               // 9.44 MB
  float* part_ml = (float*)(part_O + (size_t)1152 * 2 * 1024);   // 0.59 MB

  const float QSCALE = 0.125f * 1.44269504088896f;

  setup_kernel<<<dim3(256 + 2736), dim3(256), 0, stream>>>(X, Wq, Wk, Wv, Wo, Xb, Wb, Wob, cost, sint);
  qkv_gemm_kernel<<<dim3(64, 15), dim3(256), 0, stream>>>(Xb, Wb, qb, kb, vt);
  rope_apply_all<<<dim3((Bsz * (NH + NKV) * Slen + 255) / 256), dim3(256), 0, stream>>>(qb, pos, cost, sint, QSCALE);
  flash_attn_kernel<<<dim3(1728), dim3(128), 0, stream>>>(qb, kb, vt, ab, part_O, part_ml);
  combine_kernel<<<dim3(576), dim3(128), 0, stream>>>(part_O, part_ml, ab);
  out_gemm_kernel<<<dim3(64, 9), dim3(256), 0, stream>>>(ab, Wob, out);
}